// Round 14
// baseline (221.228 us; speedup 1.0000x reference)
//
#include <hip/hip_runtime.h>
#include <hip/hip_bf16.h>

#define TWO_PI 6.28318530717958647692f

typedef __attribute__((ext_vector_type(8))) short bf16x8;
typedef __attribute__((ext_vector_type(4))) float f32x4;

__device__ __forceinline__ unsigned short f2bf(float v) {
    __hip_bfloat16 h = __float2bfloat16(v);
    return *(unsigned short*)&h;
}

__device__ __forceinline__ bf16x8 cvt8(float4 a, float4 b) {
    bf16x8 r;
    r[0] = (short)f2bf(a.x); r[1] = (short)f2bf(a.y);
    r[2] = (short)f2bf(a.z); r[3] = (short)f2bf(a.w);
    r[4] = (short)f2bf(b.x); r[5] = (short)f2bf(b.y);
    r[6] = (short)f2bf(b.z); r[7] = (short)f2bf(b.w);
    return r;
}

// 128-col swizzle helper (row stride 128 u16 = 256B, ch = k>>3 in 0..15):
#define SWZ128(row, ch) ((((ch) & 8) | (((ch) ^ ((row) & 7)) & 7)) << 3)

// Problem: B=32, M=N=128, I=O=64, NM=16.
// R5: MFMA operands from LDS/regs. R9-R12: full MFMA chain, packed bf16
// intermediates. R13 (split k56) REGRESSED -> reverted. R14: fused k56 +
// T14 async-STAGE: head weights preloaded to registers at kernel top /
// during prior head's GEMMs, so global-load latency never sits between
// barriers.
//
// ws layout (float offsets):
//   w0cc    @ 0        : 524288 u16 [p:32][2][j:64][k:128] bf16 swz
//   w1cc    @ 262144   : 524288 u16 [hkv:32][2][o:64][k:128] bf16 swz
//   T       @ 524288   : 4194304 u32 packed bf16 (b,u,q,o)
//   A       @ 8912896  : 4194304 u32 packed bf16 (b,m,kv,i)
//   xft     @ 17301504 : 1048576 u32 packed
//   c1      @ 19398656 : 1048576 u32 packed
//   oft     @ 21495808 : 1048576 u32 packed
//   w1bt    @ 23592960 : 16384 u16  W1t[2][o:128][k:64] bf16 PRE-SWIZZLED
//   w2bt    @ 23601152 : 16384 u16  W2t[2][o:64][k:128] bf16 PRE-SWIZZLED
//   wlt_pre @ 23609344 : 4096 u16   w_lin^T bf16 pre-swizzled
//   ctb_pre @ 23611392 : 4096 u16   irfft coeff bf16 pre-swizzled
//   wdft    @ 23613440 : 4352 u16   DFT matrix [c:2][kv:16][n:136 pad] bf16
//   e2k2    @ 23615616 : 16384 u16  k2 E bf16 swz
//   e2k4    @ 23623808 : 16384 u16  k4 E bf16 swz

__global__ __launch_bounds__(256) void k0_prep(const float* __restrict__ ws0,
                                               const float* __restrict__ ws1,
                                               unsigned short* __restrict__ w0cc,
                                               unsigned short* __restrict__ w1cc)
{
    int tgt = blockIdx.x * 256 + threadIdx.x;   // 0..1048575
    int which = tgt >> 19;
    int u = tgt & 524287;
    int ps = u >> 14;          // p (w0cc) or h*16+kv (w1cc)
    int plane = (u >> 13) & 1;
    int row = (u >> 7) & 63;   // j or o
    int k = u & 127;
    int half = k >> 6, e = k & 63;
    float re, im;
    if (which == 0) {
        const float* s = (ps < 16) ? ws0 : ws1;
        int base = ((e * 64 + row) * 16 + (ps & 15)) * 2;
        re = s[base]; im = s[base + 1];
    } else {
        const float* s = ((ps >> 4) ? ws1 : ws0) + 131072;
        int base = ((e * 64 + row) * 16 + (ps & 15)) * 2;
        re = s[base]; im = s[base + 1];
    }
    float val = plane ? (half ? re : im) : (half ? -im : re);
    int ch = k >> 3;
    int dst = ps * 16384 + plane * 8192 + row * 128 + SWZ128(row, ch) + (k & 7);
    (which ? w1cc : w0cc)[dst] = f2bf(val);
}

__global__ __launch_bounds__(256) void k0b_prep(const float* __restrict__ wb1,
                                                const float* __restrict__ wf1,
                                                const float* __restrict__ wb2,
                                                const float* __restrict__ wf2,
                                                const float* __restrict__ wl,
                                                unsigned short* __restrict__ w1bt,
                                                unsigned short* __restrict__ w2bt,
                                                unsigned short* __restrict__ wlt_pre,
                                                unsigned short* __restrict__ ctb_pre,
                                                unsigned short* __restrict__ wdft,
                                                unsigned short* __restrict__ e2k2,
                                                unsigned short* __restrict__ e2k4)
{
    int tgt = blockIdx.x * 256 + threadIdx.x;   // 0..78079
    if (tgt < 16384) {
        int head = tgt >> 13;
        int o = (tgt >> 6) & 127;
        int i = tgt & 63;
        const float* src = head ? wf1 : wb1;    // [64][128]
        int dst = head * 8192 + o * 64 + (((i >> 3) ^ (o & 7)) << 3) + (i & 7);
        w1bt[dst] = f2bf(src[i * 128 + o]);
    } else if (tgt < 32768) {
        int u = tgt - 16384;
        int head = u >> 13;
        int o = (u >> 7) & 63;
        int c = u & 127;
        const float* src = head ? wf2 : wb2;    // [128][64]
        int dst = head * 8192 + o * 128 + (((c >> 3) ^ (o & 7)) << 3) + (c & 7);
        w2bt[dst] = f2bf(src[c * 64 + o]);
    } else if (tgt < 36864) {
        int u = tgt - 32768;
        int o = u >> 6, i = u & 63;
        int chunk = (i >> 3) ^ (o & 7);
        wlt_pre[o * 64 + chunk * 8 + (i & 7)] = f2bf(wl[i * 64 + o]);
    } else if (tgt < 40960) {
        int u = tgt - 36864;
        int v = u >> 5, k = u & 31;
        float val;
        if (k < 16) {
            val = (k == 0) ? (1.0f / 128.0f)
                           : (2.0f / 128.0f) * cosf(TWO_PI * k * v * (1.0f / 128.0f));
        } else {
            int q = k - 16;
            val = (q == 0) ? 0.f
                           : -(2.0f / 128.0f) * sinf(TWO_PI * q * v * (1.0f / 128.0f));
        }
        int chunk = (k >> 3) ^ ((v >> 1) & 3);
        ctb_pre[v * 32 + chunk * 8 + (k & 7)] = f2bf(val);
    } else if (tgt < 45312) {
        int u = tgt - 40960;
        int c = u / 2176;
        int rem = u - c * 2176;
        int kv = rem / 136, n = rem - (rem / 136) * 136;
        float val = 0.f;
        if (n < 128) {
            int idx = (kv * n) & 127;
            float th = (float)idx * (TWO_PI / 128.0f);
            val = c ? -sinf(th) : cosf(th);
        }
        wdft[u] = f2bf(val);
    } else if (tgt < 61696) {
        int u = tgt - 45312;
        int plane = u >> 13;
        int rem = u & 8191;
        int p = rem >> 8;
        int k = rem & 255;
        int km = (p < 16) ? p : (96 + p);
        int m = (k < 128) ? k : (k - 128);
        float th = (float)((km * m) & 127) * (TWO_PI / 128.0f);
        float c = cosf(th), s = sinf(th);
        float val = plane ? ((k < 128) ? -s : c) : ((k < 128) ? c : s);
        val *= (1.0f / 128.0f);
        int ch = k >> 3;
        int dst = plane * 8192 + p * 256 + (((ch & 24) | ((ch ^ p) & 7)) << 3) + (k & 7);
        e2k2[dst] = f2bf(val);
    } else {
        int u = tgt - 61696;
        int plane = u >> 13;
        int rem = u & 8191;
        int uu = rem >> 6;
        int k = rem & 63;
        int p = (k < 32) ? k : (k - 32);
        int km = (p < 16) ? p : (96 + p);
        float th = (float)((km * uu) & 127) * (TWO_PI / 128.0f);
        float c = cosf(th), s = sinf(th);
        float val = plane ? ((k < 32) ? s : c) : ((k < 32) ? c : -s);
        int ch = k >> 3;
        int dst = plane * 8192 + uu * 64 + (((ch ^ (uu & 7)) & 7) << 3) + (k & 7);
        e2k4[dst] = f2bf(val);
    }
}

// k1 (MFMA): A[b,m,kv,i] = sum_n W[kv,n] x[b,m,n,i], packed bf16 u32 out.
__global__ __launch_bounds__(256) void k1_dft_n(const float* __restrict__ x,
                                                const unsigned short* __restrict__ wdft,
                                                unsigned int* __restrict__ A)
{
    __shared__ __align__(16) unsigned short Xt[64 * 136];
    __shared__ __align__(16) unsigned short Wl[2 * 16 * 136];
    const int t = threadIdx.x;
    const int bm = blockIdx.x;
    {
        const uint4* wg = (const uint4*)wdft;
        uint4* wl = (uint4*)Wl;
        for (int k = t; k < 544; k += 256) wl[k] = wg[k];
    }
    {
        const float* xg = x + (size_t)bm * 8192;
        const int i = t & 63, q = t >> 6;
        #pragma unroll
        for (int pass = 0; pass < 8; ++pass) {
            int n0 = pass * 16 + q * 4;
            float v0 = xg[(n0 + 0) * 64 + i];
            float v1 = xg[(n0 + 1) * 64 + i];
            float v2 = xg[(n0 + 2) * 64 + i];
            float v3 = xg[(n0 + 3) * 64 + i];
            unsigned lo = (unsigned)f2bf(v0) | ((unsigned)f2bf(v1) << 16);
            unsigned hi = (unsigned)f2bf(v2) | ((unsigned)f2bf(v3) << 16);
            *(uint2*)&Xt[i * 136 + n0] = make_uint2(lo, hi);
        }
    }
    __syncthreads();
    const int lane = t & 63, wv = t >> 6;
    const int ar = lane & 15, kg = lane >> 4;
    f32x4 are = (f32x4){0.f, 0.f, 0.f, 0.f};
    f32x4 aim = (f32x4){0.f, 0.f, 0.f, 0.f};
    #pragma unroll
    for (int ks = 0; ks < 4; ++ks) {
        int off = ks * 32 + kg * 8;
        bf16x8 b   = *(const bf16x8*)&Xt[(wv * 16 + ar) * 136 + off];
        bf16x8 wre = *(const bf16x8*)&Wl[ar * 136 + off];
        bf16x8 wim = *(const bf16x8*)&Wl[(16 + ar) * 136 + off];
        are = __builtin_amdgcn_mfma_f32_16x16x32_bf16(wre, b, are, 0, 0, 0);
        aim = __builtin_amdgcn_mfma_f32_16x16x32_bf16(wim, b, aim, 0, 0, 0);
    }
    unsigned int* Ap = A + (size_t)bm * 1024;
    #pragma unroll
    for (int r = 0; r < 4; ++r) {
        int kv = kg * 4 + r;
        int i = wv * 16 + ar;
        Ap[kv * 64 + i] = (unsigned)f2bf(are[r]) | ((unsigned)f2bf(aim[r]) << 16);
    }
}

// k2 (MFMA): xft[p,i] = E*[ar;ai] per (b,kv). K=256 concat. Packed u32 out.
__global__ __launch_bounds__(256) void k2_dft_m(const unsigned int* __restrict__ A,
                                                const unsigned short* __restrict__ e2k2,
                                                unsigned int* __restrict__ xftp)
{
    __shared__ __align__(16) unsigned short El[16384];
    __shared__ __align__(16) unsigned short Sl[16384];
    const int t = threadIdx.x;
    const int b = blockIdx.x >> 4, kv = blockIdx.x & 15;
    {
        const uint4* eg = (const uint4*)e2k2;
        for (int k = t; k < 2048; k += 256) ((uint4*)El)[k] = eg[k];
    }
    for (int idx = t; idx < 4096; idx += 256) {
        int m2 = idx >> 6, i = idx & 63;
        int m = m2 << 1;
        unsigned a0 = A[((size_t)(b * 128 + m) * 16 + kv) * 64 + i];
        unsigned a1 = A[((size_t)(b * 128 + m + 1) * 16 + kv) * 64 + i];
        unsigned arp = (a0 & 0xffffu) | (a1 << 16);
        unsigned aip = (a0 >> 16) | (a1 & 0xffff0000u);
        int chr = m >> 3;
        *(unsigned*)&Sl[i * 256 + (((chr & 24) | ((chr ^ i) & 7)) << 3) + (m & 7)] = arp;
        int kk = 128 + m;
        int chi = kk >> 3;
        *(unsigned*)&Sl[i * 256 + (((chi & 24) | ((chi ^ i) & 7)) << 3) + (kk & 7)] = aip;
    }
    __syncthreads();
    const int lane = t & 63, wv = t >> 6;
    const int ar = lane & 15, kg = lane >> 4;
    const int pt = wv >> 1;
    const int it0 = (wv & 1) << 1;
    #pragma unroll
    for (int iti = 0; iti < 2; ++iti) {
        int it = it0 + iti;
        int prow = pt * 16 + ar;
        int irow = it * 16 + ar;
        f32x4 accre = (f32x4){0.f, 0.f, 0.f, 0.f};
        f32x4 accim = (f32x4){0.f, 0.f, 0.f, 0.f};
        #pragma unroll
        for (int ks = 0; ks < 8; ++ks) {
            int ch = ks * 4 + kg;
            int aoff = prow * 256 + (((ch & 24) | ((ch ^ prow) & 7)) << 3);
            int boff = irow * 256 + (((ch & 24) | ((ch ^ irow) & 7)) << 3);
            bf16x8 bfrag = *(const bf16x8*)&Sl[boff];
            bf16x8 fre = *(const bf16x8*)&El[aoff];
            bf16x8 fim = *(const bf16x8*)&El[8192 + aoff];
            accre = __builtin_amdgcn_mfma_f32_16x16x32_bf16(fre, bfrag, accre, 0, 0, 0);
            accim = __builtin_amdgcn_mfma_f32_16x16x32_bf16(fim, bfrag, accim, 0, 0, 0);
        }
        #pragma unroll
        for (int r = 0; r < 4; ++r) {
            int p = pt * 16 + kg * 4 + r;
            int i = it * 16 + ar;
            xftp[((size_t)(b * 32 + p) * 16 + kv) * 64 + i] =
                (unsigned)f2bf(accre[r]) | ((unsigned)f2bf(accim[r]) << 16);
        }
    }
}

// k3a (MFMA): c1[kv,j] = xft[kv,:] @ w0cc[p] per (b,p). K=128 i-concat.
__global__ __launch_bounds__(256) void k3a_spec1(const unsigned int* __restrict__ xftp,
                                                 const unsigned short* __restrict__ w0cc,
                                                 unsigned int* __restrict__ c1p)
{
    __shared__ __align__(16) unsigned short As[16 * 128];
    __shared__ __align__(16) unsigned short Ws[2 * 64 * 128];
    const int t = threadIdx.x;
    const int b = blockIdx.x >> 5, p = blockIdx.x & 31;
    {
        const uint4* wg = (const uint4*)(w0cc + (size_t)p * 16384);
        for (int k = t; k < 2048; k += 256) ((uint4*)Ws)[k] = wg[k];
    }
    for (int idx = t; idx < 512; idx += 256) {
        int kvv = idx >> 5, i2 = (idx & 31) << 1;
        const unsigned* src = xftp + ((size_t)(b * 32 + p) * 16 + kvv) * 64;
        unsigned a0 = src[i2], a1 = src[i2 + 1];
        unsigned rep = (a0 & 0xffffu) | (a1 << 16);
        unsigned imp = (a0 >> 16) | (a1 & 0xffff0000u);
        int chr = i2 >> 3;
        *(unsigned*)&As[kvv * 128 + SWZ128(kvv, chr) + (i2 & 7)] = rep;
        int kk = 64 + i2;
        int chi = kk >> 3;
        *(unsigned*)&As[kvv * 128 + SWZ128(kvv, chi) + (kk & 7)] = imp;
    }
    __syncthreads();
    const int lane = t & 63, wv = t >> 6;
    const int ar = lane & 15, kg = lane >> 4;
    const int jrow = wv * 16 + ar;
    f32x4 accre = (f32x4){0.f, 0.f, 0.f, 0.f};
    f32x4 accim = (f32x4){0.f, 0.f, 0.f, 0.f};
    #pragma unroll
    for (int ks = 0; ks < 4; ++ks) {
        int ch = ks * 4 + kg;
        bf16x8 af = *(const bf16x8*)&As[ar * 128 + SWZ128(ar, ch)];
        bf16x8 br = *(const bf16x8*)&Ws[jrow * 128 + SWZ128(jrow, ch)];
        bf16x8 bi = *(const bf16x8*)&Ws[8192 + jrow * 128 + SWZ128(jrow, ch)];
        accre = __builtin_amdgcn_mfma_f32_16x16x32_bf16(af, br, accre, 0, 0, 0);
        accim = __builtin_amdgcn_mfma_f32_16x16x32_bf16(af, bi, accim, 0, 0, 0);
    }
    unsigned int* cp = c1p + ((size_t)(b * 32 + p) * 16) * 64;
    #pragma unroll
    for (int r = 0; r < 4; ++r) {
        int kv = kg * 4 + r;
        cp[kv * 64 + wv * 16 + ar] =
            (unsigned)f2bf(accre[r]) | ((unsigned)f2bf(accim[r]) << 16);
    }
}

// k3b (MFMA): oft[pp,o] = c1[pp,:] @ w1cc[h*16+kv] per (b,h,kv). K=128 j-concat.
__global__ __launch_bounds__(256) void k3b_spec2(const unsigned int* __restrict__ c1p,
                                                 const unsigned short* __restrict__ w1cc,
                                                 unsigned int* __restrict__ oftp)
{
    __shared__ __align__(16) unsigned short As[16 * 128];
    __shared__ __align__(16) unsigned short Ws[2 * 64 * 128];
    const int t = threadIdx.x;
    int id = blockIdx.x;
    const int h = id & 1; id >>= 1;
    const int kv = id & 15; const int b = id >> 4;
    {
        const uint4* wg = (const uint4*)(w1cc + (size_t)(h * 16 + kv) * 16384);
        for (int k = t; k < 2048; k += 256) ((uint4*)Ws)[k] = wg[k];
    }
    for (int idx = t; idx < 512; idx += 256) {
        int pp = idx >> 5, j2 = (idx & 31) << 1;
        const unsigned* src = c1p + ((size_t)(b * 32 + h * 16 + pp) * 16 + kv) * 64;
        unsigned a0 = src[j2], a1 = src[j2 + 1];
        unsigned rep = (a0 & 0xffffu) | (a1 << 16);
        unsigned imp = (a0 >> 16) | (a1 & 0xffff0000u);
        int chr = j2 >> 3;
        *(unsigned*)&As[pp * 128 + SWZ128(pp, chr) + (j2 & 7)] = rep;
        int kk = 64 + j2;
        int chi = kk >> 3;
        *(unsigned*)&As[pp * 128 + SWZ128(pp, chi) + (kk & 7)] = imp;
    }
    __syncthreads();
    const int lane = t & 63, wv = t >> 6;
    const int ar = lane & 15, kg = lane >> 4;
    const int orow = wv * 16 + ar;
    f32x4 accre = (f32x4){0.f, 0.f, 0.f, 0.f};
    f32x4 accim = (f32x4){0.f, 0.f, 0.f, 0.f};
    #pragma unroll
    for (int ks = 0; ks < 4; ++ks) {
        int ch = ks * 4 + kg;
        bf16x8 af = *(const bf16x8*)&As[ar * 128 + SWZ128(ar, ch)];
        bf16x8 br = *(const bf16x8*)&Ws[orow * 128 + SWZ128(orow, ch)];
        bf16x8 bi = *(const bf16x8*)&Ws[8192 + orow * 128 + SWZ128(orow, ch)];
        accre = __builtin_amdgcn_mfma_f32_16x16x32_bf16(af, br, accre, 0, 0, 0);
        accim = __builtin_amdgcn_mfma_f32_16x16x32_bf16(af, bi, accim, 0, 0, 0);
    }
    #pragma unroll
    for (int r = 0; r < 4; ++r) {
        int pp = kg * 4 + r;
        oftp[((size_t)(b * 32 + h * 16 + pp) * 16 + kv) * 64 + orow] =
            (unsigned)f2bf(accre[r]) | ((unsigned)f2bf(accim[r]) << 16);
    }
}

// k4 (MFMA): T[u,o] = E*[re;im] per (b,q). K=64 concat.
__global__ __launch_bounds__(256) void k4_idft_m(const unsigned int* __restrict__ oftp,
                                                 const unsigned short* __restrict__ e2k4,
                                                 unsigned int* __restrict__ T)
{
    __shared__ __align__(16) unsigned short El[16384];
    __shared__ __align__(16) unsigned short Sl[4096];
    const int t = threadIdx.x;
    const int b = blockIdx.x >> 4, q = blockIdx.x & 15;
    {
        const uint4* eg = (const uint4*)e2k4;
        for (int k = t; k < 2048; k += 256) ((uint4*)El)[k] = eg[k];
    }
    for (int idx = t; idx < 1024; idx += 256) {
        int p2 = idx >> 6, o = idx & 63;
        int p = p2 << 1;
        unsigned a0 = oftp[((size_t)(b * 32 + p) * 16 + q) * 64 + o];
        unsigned a1 = oftp[((size_t)(b * 32 + p + 1) * 16 + q) * 64 + o];
        unsigned rep = (a0 & 0xffffu) | (a1 << 16);
        unsigned imp = (a0 >> 16) | (a1 & 0xffff0000u);
        int chr = p >> 3;
        *(unsigned*)&Sl[o * 64 + ((chr ^ (o & 7)) << 3) + (p & 7)] = rep;
        int kk = 32 + p;
        int chi = kk >> 3;
        *(unsigned*)&Sl[o * 64 + ((chi ^ (o & 7)) << 3) + (kk & 7)] = imp;
    }
    __syncthreads();
    const int lane = t & 63, wv = t >> 6;
    const int ar = lane & 15, kg = lane >> 4;
    unsigned int* Tp = T + ((size_t)b * 128) * 1024 + (size_t)q * 64;
    #pragma unroll
    for (int uti = 0; uti < 2; ++uti) {
        int ut = wv * 2 + uti;
        int urow = ut * 16 + ar;
        int aswz = urow & 7;
        #pragma unroll
        for (int ot = 0; ot < 4; ++ot) {
            int orow = ot * 16 + ar;
            f32x4 accre = (f32x4){0.f, 0.f, 0.f, 0.f};
            f32x4 accim = (f32x4){0.f, 0.f, 0.f, 0.f};
            #pragma unroll
            for (int ks = 0; ks < 2; ++ks) {
                int ch = ks * 4 + kg;
                int aoff = urow * 64 + ((ch ^ aswz) << 3);
                int boff = orow * 64 + ((ch ^ (orow & 7)) << 3);
                bf16x8 bfrag = *(const bf16x8*)&Sl[boff];
                bf16x8 fre = *(const bf16x8*)&El[aoff];
                bf16x8 fim = *(const bf16x8*)&El[8192 + aoff];
                accre = __builtin_amdgcn_mfma_f32_16x16x32_bf16(fre, bfrag, accre, 0, 0, 0);
                accim = __builtin_amdgcn_mfma_f32_16x16x32_bf16(fim, bfrag, accim, 0, 0, 0);
            }
            #pragma unroll
            for (int r = 0; r < 4; ++r) {
                int u = ut * 16 + kg * 4 + r;
                int o = ot * 16 + ar;
                Tp[(size_t)u * 1024 + o] =
                    (unsigned)f2bf(accre[r]) | ((unsigned)f2bf(accim[r]) << 16);
            }
        }
    }
}

// k56: 2 bm per block (grid 2048). LDS 80K -> 2 blocks/CU. 5 barriers.
// R14: T14 async-STAGE for head weights — head-0 loads issued at kernel top
// (drain under table-staging + phase A), head-1 loads issued right after the
// head-0 ds_writes (drain under head-0 GEMMs). No naked global-load latency
// between barriers.
__global__ __launch_bounds__(256) void k56_fused(
    const float* __restrict__ x, const unsigned int* __restrict__ Tg,
    const float* __restrict__ bl,
    const unsigned short* __restrict__ ctb_pre, const unsigned short* __restrict__ wlt_pre,
    const unsigned short* __restrict__ w1bt, const unsigned short* __restrict__ w2bt,
    const float* __restrict__ bb1, const float* __restrict__ bb2,
    const float* __restrict__ bf1, const float* __restrict__ bf2,
    float* __restrict__ out)
{
    __shared__ __align__(16) unsigned char U[32768];
    __shared__ __align__(16) unsigned short ys[2][8192];
    __shared__ __align__(16) unsigned short hs[8192];

    unsigned short* Ctb = (unsigned short*)U;
    unsigned short* wlt = (unsigned short*)(U + 8192);
    unsigned short* Tpk = (unsigned short*)(U + 16384);
    unsigned short* w1s = (unsigned short*)U;
    unsigned short* w2s = (unsigned short*)(U + 16384);

    const int t = threadIdx.x;
    const int bm0 = blockIdx.x << 1;
    const int lane = t & 63, wv = t >> 6;
    const int ar = lane & 15, kg = lane >> 4;
    const int R0 = wv * 32;

    // ---- EARLY: head-0 weight loads into registers (T14 issue-early) ----
    uint4 w1r[4], w2r[4];
    {
        const uint4* g1 = (const uint4*)w1bt;
        const uint4* g2 = (const uint4*)w2bt;
        #pragma unroll
        for (int k = 0; k < 4; ++k) {
            w1r[k] = g1[t + k * 256];
            w2r[k] = g2[t + k * 256];
        }
    }
    // ---- EARLY: x loads for both bm ----
    float4 xr[2][2][4];
    #pragma unroll
    for (int g = 0; g < 2; ++g)
        #pragma unroll
        for (int rt = 0; rt < 2; ++rt) {
            const float* xp = x + (size_t)(bm0 + g) * 8192 + (R0 + rt * 16 + ar) * 64 + kg * 8;
            xr[g][rt][0] = *(const float4*)(xp);
            xr[g][rt][1] = *(const float4*)(xp + 4);
            xr[g][rt][2] = *(const float4*)(xp + 32);
            xr[g][rt][3] = *(const float4*)(xp + 36);
        }

    // ---- stage: Ctb/wlt straight copies; Tpk pack (2 bm) ----
    {
        const uint4* cg = (const uint4*)ctb_pre;
        for (int k = t; k < 512; k += 256) ((uint4*)Ctb)[k] = cg[k];
        const uint4* wg = (const uint4*)wlt_pre;
        for (int k = t; k < 512; k += 256) ((uint4*)wlt)[k] = wg[k];
        for (int idx = t; idx < 2048; idx += 256) {
            int g = idx >> 10, rem = idx & 1023;
            int q = rem >> 6, o = rem & 63;
            unsigned v = Tg[(size_t)(bm0 + g) * 1024 + rem];
            int f = (o >> 1) & 3;
            unsigned short* Tp = Tpk + g * 2048;
            Tp[o * 32 + (((q >> 3) ^ f) << 3) + (q & 7)] = (unsigned short)(v & 0xffffu);
            Tp[o * 32 + (((2 + (q >> 3)) ^ f) << 3) + (q & 7)] = (unsigned short)(v >> 16);
        }
    }
    __syncthreads();   // B1

    float biasl[4];
    #pragma unroll
    for (int ct = 0; ct < 4; ++ct) biasl[ct] = bl[ct * 16 + ar];

    // ---- phase A: y for both bm via MFMA ----
    #pragma unroll
    for (int g = 0; g < 2; ++g) {
        const unsigned short* Tp = Tpk + g * 2048;
        #pragma unroll
        for (int rt = 0; rt < 2; ++rt) {
            const int vrow = R0 + rt * 16 + ar;
            bf16x8 a0 = cvt8(xr[g][rt][0], xr[g][rt][1]);
            bf16x8 a1 = cvt8(xr[g][rt][2], xr[g][rt][3]);
            bf16x8 asp = *(const bf16x8*)&Ctb[vrow * 32 + ((kg ^ ((vrow >> 1) & 3)) << 3)];
            f32x4 acc[4];
            #pragma unroll
            for (int ct = 0; ct < 4; ++ct) acc[ct] = (f32x4){0.f, 0.f, 0.f, 0.f};
            #pragma unroll
            for (int ct = 0; ct < 4; ++ct) {
                int o = ct * 16 + ar;
                bf16x8 b0 = *(const bf16x8*)&wlt[o * 64 + ((kg ^ (o & 7)) << 3)];
                bf16x8 b1 = *(const bf16x8*)&wlt[o * 64 + (((4 + kg) ^ (o & 7)) << 3)];
                bf16x8 bsp = *(const bf16x8*)&Tp[o * 32 + ((kg ^ ((o >> 1) & 3)) << 3)];
                acc[ct] = __builtin_amdgcn_mfma_f32_16x16x32_bf16(a0, b0, acc[ct], 0, 0, 0);
                acc[ct] = __builtin_amdgcn_mfma_f32_16x16x32_bf16(a1, b1, acc[ct], 0, 0, 0);
                acc[ct] = __builtin_amdgcn_mfma_f32_16x16x32_bf16(asp, bsp, acc[ct], 0, 0, 0);
            }
            #pragma unroll
            for (int ct = 0; ct < 4; ++ct) {
                int col = ct * 16 + ar;
                #pragma unroll
                for (int r = 0; r < 4; ++r) {
                    int row = R0 + rt * 16 + kg * 4 + r;
                    float v = fmaxf(acc[ct][r] + biasl[ct], 0.f);
                    ys[g][row * 64 + (((col >> 3) ^ (row & 7)) << 3) + (col & 7)] = f2bf(v);
                }
            }
        }
    }
    __syncthreads();   // B2: tables dead -> U becomes w1s|w2s

    unsigned short* hw = hs + wv * 2048;
    for (int head = 0; head < 2; ++head) {
        // ds_write the pre-loaded weights (no global latency here)
        #pragma unroll
        for (int k = 0; k < 4; ++k) {
            ((uint4*)w1s)[t + k * 256] = w1r[k];
            ((uint4*)w2s)[t + k * 256] = w2r[k];
        }
        if (head == 0) {
            // issue head-1 loads now; they drain under head-0 GEMMs
            const uint4* g1 = (const uint4*)(w1bt + 8192);
            const uint4* g2 = (const uint4*)(w2bt + 8192);
            #pragma unroll
            for (int k = 0; k < 4; ++k) {
                w1r[k] = g1[t + k * 256];
                w2r[k] = g2[t + k * 256];
            }
        }
        const float* B1 = head ? bf1 : bb1;
        const float* B2 = head ? bf2 : bb2;
        float bias1[8], bias2[4];
        #pragma unroll
        for (int c = 0; c < 8; ++c) bias1[c] = B1[c * 16 + ar];
        #pragma unroll
        for (int c = 0; c < 4; ++c) bias2[c] = B2[c * 16 + ar];
        __syncthreads();   // B3 / B5: weights visible

        #pragma unroll
        for (int g = 0; g < 2; ++g) {
            #pragma unroll
            for (int rt = 0; rt < 2; ++rt) {
                const int rowbase = R0 + rt * 16;
                const int yrow = rowbase + ar;
                bf16x8 ya0 = *(const bf16x8*)&ys[g][yrow * 64 + ((kg ^ (yrow & 7)) << 3)];
                bf16x8 ya1 = *(const bf16x8*)&ys[g][yrow * 64 + (((4 + kg) ^ (yrow & 7)) << 3)];
                f32x4 acc1[8];
                #pragma unroll
                for (int ct = 0; ct < 8; ++ct) acc1[ct] = (f32x4){0.f, 0.f, 0.f, 0.f};
                #pragma unroll
                for (int ct = 0; ct < 8; ++ct) {
                    int brow = ct * 16 + ar;
                    bf16x8 b0 = *(const bf16x8*)&w1s[brow * 64 + ((kg ^ (brow & 7)) << 3)];
                    bf16x8 b1 = *(const bf16x8*)&w1s[brow * 64 + (((4 + kg) ^ (brow & 7)) << 3)];
                    acc1[ct] = __builtin_amdgcn_mfma_f32_16x16x32_bf16(ya0, b0, acc1[ct], 0, 0, 0);
                    acc1[ct] = __builtin_amdgcn_mfma_f32_16x16x32_bf16(ya1, b1, acc1[ct], 0, 0, 0);
                }
                #pragma unroll
                for (int ct = 0; ct < 8; ++ct) {
                    #pragma unroll
                    for (int r = 0; r < 4; ++r) {
                        int row = kg * 4 + r;
                        int col = ct * 16 + ar;
                        float v = fmaxf(acc1[ct][r] + bias1[ct], 0.f);
                        hw[row * 128 + (((col >> 3) ^ (row & 7)) << 3) + (col & 7)] = f2bf(v);
                    }
                }
                f32x4 acc2[4];
                #pragma unroll
                for (int ct = 0; ct < 4; ++ct) acc2[ct] = (f32x4){0.f, 0.f, 0.f, 0.f};
                #pragma unroll
                for (int ks = 0; ks < 4; ++ks) {
                    bf16x8 a = *(const bf16x8*)&hw[ar * 128 + (((ks * 4 + kg) ^ (ar & 7)) << 3)];
                    #pragma unroll
                    for (int ct = 0; ct < 4; ++ct) {
                        int brow = ct * 16 + ar;
                        bf16x8 b = *(const bf16x8*)&w2s[brow * 128 + (((ks * 4 + kg) ^ (ar & 7)) << 3)];
                        acc2[ct] = __builtin_amdgcn_mfma_f32_16x16x32_bf16(a, b, acc2[ct], 0, 0, 0);
                    }
                }
                float* og = out + (size_t)head * 33554432u + (size_t)(bm0 + g) * 8192;
                #pragma unroll
                for (int ct = 0; ct < 4; ++ct) {
                    #pragma unroll
                    for (int r = 0; r < 4; ++r)
                        og[(size_t)(rowbase + kg * 4 + r) * 64 + ct * 16 + ar] =
                            acc2[ct][r] + bias2[ct];
                }
            }
        }
        if (head == 0) __syncthreads();   // B4: weight reads done before restage
    }
}

extern "C" void kernel_launch(void* const* d_in, const int* in_sizes, int n_in,
                              void* d_out, int out_size, void* d_ws, size_t ws_size,
                              hipStream_t stream)
{
    (void)in_sizes; (void)n_in; (void)out_size; (void)ws_size;
    const float* x   = (const float*)d_in[0];
    const float* ws0 = (const float*)d_in[1];
    const float* ws1 = (const float*)d_in[2];
    const float* wl  = (const float*)d_in[3];
    const float* bl  = (const float*)d_in[4];
    const float* wb1 = (const float*)d_in[5];
    const float* bb1 = (const float*)d_in[6];
    const float* wb2 = (const float*)d_in[7];
    const float* bb2 = (const float*)d_in[8];
    const float* wf1 = (const float*)d_in[9];
    const float* bf1 = (const float*)d_in[10];
    const float* wf2 = (const float*)d_in[11];
    const float* bf2 = (const float*)d_in[12];
    float* out = (float*)d_out;

    float* ws = (float*)d_ws;
    unsigned short* w0cc = (unsigned short*)ws;              // 524288 u16
    unsigned short* w1cc = (unsigned short*)(ws + 262144);   // 524288 u16
    unsigned int* Tb   = (unsigned int*)(ws + 524288);       // 4194304 u32
    unsigned int* Ab   = (unsigned int*)(ws + 8912896);      // 4194304 u32
    unsigned int* xftp = (unsigned int*)(ws + 17301504);     // 1048576 u32
    unsigned int* c1p  = (unsigned int*)(ws + 19398656);     // 1048576 u32
    unsigned int* oftp = (unsigned int*)(ws + 21495808);     // 1048576 u32
    unsigned short* w1bt    = (unsigned short*)(ws + 23592960);  // 16384 u16
    unsigned short* w2bt    = (unsigned short*)(ws + 23601152);  // 16384 u16
    unsigned short* wlt_pre = (unsigned short*)(ws + 23609344);  // 4096 u16
    unsigned short* ctb_pre = (unsigned short*)(ws + 23611392);  // 4096 u16
    unsigned short* wdft    = (unsigned short*)(ws + 23613440);  // 4352 u16
    unsigned short* e2k2    = (unsigned short*)(ws + 23615616);  // 16384 u16
    unsigned short* e2k4    = (unsigned short*)(ws + 23623808);  // 16384 u16

    k0_prep    <<<4096, 256, 0, stream>>>(ws0, ws1, w0cc, w1cc);
    k0b_prep   <<<305,  256, 0, stream>>>(wb1, wf1, wb2, wf2, wl,
                                          w1bt, w2bt, wlt_pre, ctb_pre, wdft,
                                          e2k2, e2k4);
    k1_dft_n   <<<4096, 256, 0, stream>>>(x, wdft, Ab);
    k2_dft_m   <<<512,  256, 0, stream>>>(Ab, e2k2, xftp);
    k3a_spec1  <<<1024, 256, 0, stream>>>(xftp, w0cc, c1p);
    k3b_spec2  <<<1024, 256, 0, stream>>>(c1p, w1cc, oftp);
    k4_idft_m  <<<512,  256, 0, stream>>>(oftp, e2k4, Tb);
    k56_fused  <<<2048, 256, 0, stream>>>(x, Tb, bl, ctb_pre, wlt_pre,
                                          w1bt, w2bt, bb1, bb2, bf1, bf2, out);
}

// Round 15
// 194.358 us; speedup vs baseline: 1.1382x; 1.1382x over previous
//
#include <hip/hip_runtime.h>
#include <hip/hip_bf16.h>

#define TWO_PI 6.28318530717958647692f

typedef __attribute__((ext_vector_type(8))) short bf16x8;
typedef __attribute__((ext_vector_type(4))) float f32x4;

__device__ __forceinline__ unsigned short f2bf(float v) {
    __hip_bfloat16 h = __float2bfloat16(v);
    return *(unsigned short*)&h;
}

__device__ __forceinline__ bf16x8 cvt8(float4 a, float4 b) {
    bf16x8 r;
    r[0] = (short)f2bf(a.x); r[1] = (short)f2bf(a.y);
    r[2] = (short)f2bf(a.z); r[3] = (short)f2bf(a.w);
    r[4] = (short)f2bf(b.x); r[5] = (short)f2bf(b.y);
    r[6] = (short)f2bf(b.z); r[7] = (short)f2bf(b.w);
    return r;
}

// 128-col swizzle helper (row stride 128 u16 = 256B, ch = k>>3 in 0..15):
//   slot = ((ch&8) | ((ch^row)&7)) << 3  |  (k&7)
#define SWZ128(row, ch) ((((ch) & 8) | (((ch) ^ ((row) & 7)) & 7)) << 3)

// Problem: B=32, M=N=128, I=O=64, NM=16.
// Spectral path keeps km in {0..15,112..127} (p=0..31), kn=0..15 (q).
// Spectral branch contributes ~1e-6 abs to y -> bf16 anywhere in it is free.
// A, T, xft, c1, oft are packed bf16 pairs (u32: re low, im high).
//
// R5: MFMA operands from LDS/regs only. R9: k1 MFMA. R10: k56 2-bm/block.
// R11: k2/k4 MFMA. R12: k3a/k3b MFMA via K-concat. (BEST = 191 us)
// R13 (k56 split, y HBM round-trip): REGRESSED -> reverted.
// R14 (k56 reg-preload of weights): SPILLED to scratch (+130MB writes) -> reverted.
// R15 = exact R12.
//
// ws layout (float offsets):
//   w0cc    @ 0        : 524288 u16 [p:32][2][j:64][k:128] bf16 swz
//   w1cc    @ 262144   : 524288 u16 [hkv:32][2][o:64][k:128] bf16 swz
//   T       @ 524288   : 4194304 u32 packed bf16 (b,u,q,o)
//   A       @ 8912896  : 4194304 u32 packed bf16 (b,m,kv,i)
//   xft     @ 17301504 : 1048576 u32 packed (b,p,kv,i)
//   c1      @ 19398656 : 1048576 u32 packed (b,p,kv,j)
//   oft     @ 21495808 : 1048576 u32 packed (b,p,kv,o)
//   w1bt    @ 23592960 : 16384 u16  W1t[2][o:128][k:64] bf16 PRE-SWIZZLED
//   w2bt    @ 23601152 : 16384 u16  W2t[2][o:64][k:128] bf16 PRE-SWIZZLED
//   wlt_pre @ 23609344 : 4096 u16   w_lin^T bf16 pre-swizzled
//   ctb_pre @ 23611392 : 4096 u16   irfft coeff bf16 pre-swizzled
//   wdft    @ 23613440 : 4352 u16   DFT matrix [c:2][kv:16][n:136 pad] bf16
//   e2k2    @ 23615616 : 16384 u16  k2 E [2][p:32][k:256] bf16 swz, 1/128 folded
//   e2k4    @ 23623808 : 16384 u16  k4 E [2][u:128][k:64] bf16 swz

// k0: K-concat bf16 pre-swizzled spectral weights.
__global__ __launch_bounds__(256) void k0_prep(const float* __restrict__ ws0,
                                               const float* __restrict__ ws1,
                                               unsigned short* __restrict__ w0cc,
                                               unsigned short* __restrict__ w1cc)
{
    int tgt = blockIdx.x * 256 + threadIdx.x;   // 0..1048575
    int which = tgt >> 19;
    int u = tgt & 524287;
    int ps = u >> 14;          // p (w0cc) or h*16+kv (w1cc)
    int plane = (u >> 13) & 1;
    int row = (u >> 7) & 63;   // j or o
    int k = u & 127;
    int half = k >> 6, e = k & 63;
    float re, im;
    if (which == 0) {
        const float* s = (ps < 16) ? ws0 : ws1;          // f=0 plane
        int base = ((e * 64 + row) * 16 + (ps & 15)) * 2; // i=e, j=row
        re = s[base]; im = s[base + 1];
    } else {
        const float* s = ((ps >> 4) ? ws1 : ws0) + 131072; // f=1 plane
        int base = ((e * 64 + row) * 16 + (ps & 15)) * 2;  // j=e, o=row
        re = s[base]; im = s[base + 1];
    }
    float val = plane ? (half ? re : im) : (half ? -im : re);
    int ch = k >> 3;
    int dst = ps * 16384 + plane * 8192 + row * 128 + SWZ128(row, ch) + (k & 7);
    (which ? w1cc : w0cc)[dst] = f2bf(val);
}

// weights + tables (pre-swizzled where consumed from LDS)
__global__ __launch_bounds__(256) void k0b_prep(const float* __restrict__ wb1,
                                                const float* __restrict__ wf1,
                                                const float* __restrict__ wb2,
                                                const float* __restrict__ wf2,
                                                const float* __restrict__ wl,
                                                unsigned short* __restrict__ w1bt,
                                                unsigned short* __restrict__ w2bt,
                                                unsigned short* __restrict__ wlt_pre,
                                                unsigned short* __restrict__ ctb_pre,
                                                unsigned short* __restrict__ wdft,
                                                unsigned short* __restrict__ e2k2,
                                                unsigned short* __restrict__ e2k4)
{
    int tgt = blockIdx.x * 256 + threadIdx.x;   // 0..78079
    if (tgt < 16384) {
        int head = tgt >> 13;
        int o = (tgt >> 6) & 127;
        int i = tgt & 63;
        const float* src = head ? wf1 : wb1;    // [64][128]
        int dst = head * 8192 + o * 64 + (((i >> 3) ^ (o & 7)) << 3) + (i & 7);
        w1bt[dst] = f2bf(src[i * 128 + o]);
    } else if (tgt < 32768) {
        int u = tgt - 16384;
        int head = u >> 13;
        int o = (u >> 7) & 63;
        int c = u & 127;
        const float* src = head ? wf2 : wb2;    // [128][64]
        int dst = head * 8192 + o * 128 + (((c >> 3) ^ (o & 7)) << 3) + (c & 7);
        w2bt[dst] = f2bf(src[c * 64 + o]);
    } else if (tgt < 36864) {
        int u = tgt - 32768;                    // 0..4095
        int o = u >> 6, i = u & 63;
        int chunk = (i >> 3) ^ (o & 7);
        wlt_pre[o * 64 + chunk * 8 + (i & 7)] = f2bf(wl[i * 64 + o]);
    } else if (tgt < 40960) {
        int u = tgt - 36864;                    // 0..4095
        int v = u >> 5, k = u & 31;             // v 0..127, k 0..31
        float val;
        if (k < 16) {
            val = (k == 0) ? (1.0f / 128.0f)
                           : (2.0f / 128.0f) * cosf(TWO_PI * k * v * (1.0f / 128.0f));
        } else {
            int q = k - 16;
            val = (q == 0) ? 0.f
                           : -(2.0f / 128.0f) * sinf(TWO_PI * q * v * (1.0f / 128.0f));
        }
        int chunk = (k >> 3) ^ ((v >> 1) & 3);
        ctb_pre[v * 32 + chunk * 8 + (k & 7)] = f2bf(val);
    } else if (tgt < 45312) {
        int u = tgt - 40960;                    // 0..4351
        int c = u / 2176;
        int rem = u - c * 2176;
        int kv = rem / 136, n = rem - (rem / 136) * 136;
        float val = 0.f;
        if (n < 128) {
            int idx = (kv * n) & 127;
            float th = (float)idx * (TWO_PI / 128.0f);
            val = c ? -sinf(th) : cosf(th);
        }
        wdft[u] = f2bf(val);
    } else if (tgt < 61696) {
        // k2 E: [plane:2][p:32][k:256] swz; plane0=[c|s]/128, plane1=[-s|c]/128
        int u = tgt - 45312;
        int plane = u >> 13;
        int rem = u & 8191;
        int p = rem >> 8;
        int k = rem & 255;
        int km = (p < 16) ? p : (96 + p);
        int m = (k < 128) ? k : (k - 128);
        float th = (float)((km * m) & 127) * (TWO_PI / 128.0f);
        float c = cosf(th), s = sinf(th);
        float val = plane ? ((k < 128) ? -s : c) : ((k < 128) ? c : s);
        val *= (1.0f / 128.0f);
        int ch = k >> 3;
        int dst = plane * 8192 + p * 256 + (((ch & 24) | ((ch ^ p) & 7)) << 3) + (k & 7);
        e2k2[dst] = f2bf(val);
    } else {
        // k4 E: [plane:2][u:128][k:64] swz; plane0=[c|-s], plane1=[s|c]
        int u = tgt - 61696;
        int plane = u >> 13;
        int rem = u & 8191;
        int uu = rem >> 6;
        int k = rem & 63;
        int p = (k < 32) ? k : (k - 32);
        int km = (p < 16) ? p : (96 + p);
        float th = (float)((km * uu) & 127) * (TWO_PI / 128.0f);
        float c = cosf(th), s = sinf(th);
        float val = plane ? ((k < 32) ? s : c) : ((k < 32) ? c : -s);
        int ch = k >> 3;
        int dst = plane * 8192 + uu * 64 + (((ch ^ (uu & 7)) & 7) << 3) + (k & 7);
        e2k4[dst] = f2bf(val);
    }
}

// k1 (MFMA): A[b,m,kv,i] = sum_n W[kv,n] x[b,m,n,i], packed bf16 u32 out.
__global__ __launch_bounds__(256) void k1_dft_n(const float* __restrict__ x,
                                                const unsigned short* __restrict__ wdft,
                                                unsigned int* __restrict__ A)
{
    __shared__ __align__(16) unsigned short Xt[64 * 136];    // 17408 B
    __shared__ __align__(16) unsigned short Wl[2 * 16 * 136];//  8704 B
    const int t = threadIdx.x;
    const int bm = blockIdx.x;
    {
        const uint4* wg = (const uint4*)wdft;
        uint4* wl = (uint4*)Wl;
        for (int k = t; k < 544; k += 256) wl[k] = wg[k];
    }
    {
        const float* xg = x + (size_t)bm * 8192;
        const int i = t & 63, q = t >> 6;
        #pragma unroll
        for (int pass = 0; pass < 8; ++pass) {
            int n0 = pass * 16 + q * 4;
            float v0 = xg[(n0 + 0) * 64 + i];
            float v1 = xg[(n0 + 1) * 64 + i];
            float v2 = xg[(n0 + 2) * 64 + i];
            float v3 = xg[(n0 + 3) * 64 + i];
            unsigned lo = (unsigned)f2bf(v0) | ((unsigned)f2bf(v1) << 16);
            unsigned hi = (unsigned)f2bf(v2) | ((unsigned)f2bf(v3) << 16);
            *(uint2*)&Xt[i * 136 + n0] = make_uint2(lo, hi);
        }
    }
    __syncthreads();
    const int lane = t & 63, wv = t >> 6;
    const int ar = lane & 15, kg = lane >> 4;
    f32x4 are = (f32x4){0.f, 0.f, 0.f, 0.f};
    f32x4 aim = (f32x4){0.f, 0.f, 0.f, 0.f};
    #pragma unroll
    for (int ks = 0; ks < 4; ++ks) {
        int off = ks * 32 + kg * 8;
        bf16x8 b   = *(const bf16x8*)&Xt[(wv * 16 + ar) * 136 + off];
        bf16x8 wre = *(const bf16x8*)&Wl[ar * 136 + off];
        bf16x8 wim = *(const bf16x8*)&Wl[(16 + ar) * 136 + off];
        are = __builtin_amdgcn_mfma_f32_16x16x32_bf16(wre, b, are, 0, 0, 0);
        aim = __builtin_amdgcn_mfma_f32_16x16x32_bf16(wim, b, aim, 0, 0, 0);
    }
    unsigned int* Ap = A + (size_t)bm * 1024;
    #pragma unroll
    for (int r = 0; r < 4; ++r) {
        int kv = kg * 4 + r;
        int i = wv * 16 + ar;
        Ap[kv * 64 + i] = (unsigned)f2bf(are[r]) | ((unsigned)f2bf(aim[r]) << 16);
    }
}

// k2 (MFMA): xft[p,i] = E*[ar;ai] per (b,kv). K=256 concat. Packed u32 out.
__global__ __launch_bounds__(256) void k2_dft_m(const unsigned int* __restrict__ A,
                                                const unsigned short* __restrict__ e2k2,
                                                unsigned int* __restrict__ xftp)
{
    __shared__ __align__(16) unsigned short El[16384];  // [2][32][256] swz, 32KB
    __shared__ __align__(16) unsigned short Sl[16384];  // [i:64][k:256] swz, 32KB
    const int t = threadIdx.x;
    const int b = blockIdx.x >> 4, kv = blockIdx.x & 15;
    {
        const uint4* eg = (const uint4*)e2k2;
        for (int k = t; k < 2048; k += 256) ((uint4*)El)[k] = eg[k];
    }
    for (int idx = t; idx < 4096; idx += 256) {
        int m2 = idx >> 6, i = idx & 63;
        int m = m2 << 1;
        unsigned a0 = A[((size_t)(b * 128 + m) * 16 + kv) * 64 + i];
        unsigned a1 = A[((size_t)(b * 128 + m + 1) * 16 + kv) * 64 + i];
        unsigned arp = (a0 & 0xffffu) | (a1 << 16);
        unsigned aip = (a0 >> 16) | (a1 & 0xffff0000u);
        int chr = m >> 3;
        *(unsigned*)&Sl[i * 256 + (((chr & 24) | ((chr ^ i) & 7)) << 3) + (m & 7)] = arp;
        int kk = 128 + m;
        int chi = kk >> 3;
        *(unsigned*)&Sl[i * 256 + (((chi & 24) | ((chi ^ i) & 7)) << 3) + (kk & 7)] = aip;
    }
    __syncthreads();
    const int lane = t & 63, wv = t >> 6;
    const int ar = lane & 15, kg = lane >> 4;
    const int pt = wv >> 1;
    const int it0 = (wv & 1) << 1;
    #pragma unroll
    for (int iti = 0; iti < 2; ++iti) {
        int it = it0 + iti;
        int prow = pt * 16 + ar;
        int irow = it * 16 + ar;
        f32x4 accre = (f32x4){0.f, 0.f, 0.f, 0.f};
        f32x4 accim = (f32x4){0.f, 0.f, 0.f, 0.f};
        #pragma unroll
        for (int ks = 0; ks < 8; ++ks) {
            int ch = ks * 4 + kg;
            int aoff = prow * 256 + (((ch & 24) | ((ch ^ prow) & 7)) << 3);
            int boff = irow * 256 + (((ch & 24) | ((ch ^ irow) & 7)) << 3);
            bf16x8 bfrag = *(const bf16x8*)&Sl[boff];
            bf16x8 fre = *(const bf16x8*)&El[aoff];
            bf16x8 fim = *(const bf16x8*)&El[8192 + aoff];
            accre = __builtin_amdgcn_mfma_f32_16x16x32_bf16(fre, bfrag, accre, 0, 0, 0);
            accim = __builtin_amdgcn_mfma_f32_16x16x32_bf16(fim, bfrag, accim, 0, 0, 0);
        }
        #pragma unroll
        for (int r = 0; r < 4; ++r) {
            int p = pt * 16 + kg * 4 + r;
            int i = it * 16 + ar;
            xftp[((size_t)(b * 32 + p) * 16 + kv) * 64 + i] =
                (unsigned)f2bf(accre[r]) | ((unsigned)f2bf(accim[r]) << 16);
        }
    }
}

// k3a (MFMA): c1[kv,j] = xft[kv,:] @ w0cc[p] per (b,p). K=128 i-concat.
__global__ __launch_bounds__(256) void k3a_spec1(const unsigned int* __restrict__ xftp,
                                                 const unsigned short* __restrict__ w0cc,
                                                 unsigned int* __restrict__ c1p)
{
    __shared__ __align__(16) unsigned short As[16 * 128];
    __shared__ __align__(16) unsigned short Ws[2 * 64 * 128];
    const int t = threadIdx.x;
    const int b = blockIdx.x >> 5, p = blockIdx.x & 31;
    {
        const uint4* wg = (const uint4*)(w0cc + (size_t)p * 16384);
        for (int k = t; k < 2048; k += 256) ((uint4*)Ws)[k] = wg[k];
    }
    for (int idx = t; idx < 512; idx += 256) {
        int kvv = idx >> 5, i2 = (idx & 31) << 1;
        const unsigned* src = xftp + ((size_t)(b * 32 + p) * 16 + kvv) * 64;
        unsigned a0 = src[i2], a1 = src[i2 + 1];
        unsigned rep = (a0 & 0xffffu) | (a1 << 16);
        unsigned imp = (a0 >> 16) | (a1 & 0xffff0000u);
        int chr = i2 >> 3;
        *(unsigned*)&As[kvv * 128 + SWZ128(kvv, chr) + (i2 & 7)] = rep;
        int kk = 64 + i2;
        int chi = kk >> 3;
        *(unsigned*)&As[kvv * 128 + SWZ128(kvv, chi) + (kk & 7)] = imp;
    }
    __syncthreads();
    const int lane = t & 63, wv = t >> 6;
    const int ar = lane & 15, kg = lane >> 4;
    const int jrow = wv * 16 + ar;
    f32x4 accre = (f32x4){0.f, 0.f, 0.f, 0.f};
    f32x4 accim = (f32x4){0.f, 0.f, 0.f, 0.f};
    #pragma unroll
    for (int ks = 0; ks < 4; ++ks) {
        int ch = ks * 4 + kg;
        bf16x8 af = *(const bf16x8*)&As[ar * 128 + SWZ128(ar, ch)];
        bf16x8 br = *(const bf16x8*)&Ws[jrow * 128 + SWZ128(jrow, ch)];
        bf16x8 bi = *(const bf16x8*)&Ws[8192 + jrow * 128 + SWZ128(jrow, ch)];
        accre = __builtin_amdgcn_mfma_f32_16x16x32_bf16(af, br, accre, 0, 0, 0);
        accim = __builtin_amdgcn_mfma_f32_16x16x32_bf16(af, bi, accim, 0, 0, 0);
    }
    unsigned int* cp = c1p + ((size_t)(b * 32 + p) * 16) * 64;
    #pragma unroll
    for (int r = 0; r < 4; ++r) {
        int kv = kg * 4 + r;
        cp[kv * 64 + wv * 16 + ar] =
            (unsigned)f2bf(accre[r]) | ((unsigned)f2bf(accim[r]) << 16);
    }
}

// k3b (MFMA): oft[pp,o] = c1[pp,:] @ w1cc[h*16+kv] per (b,h,kv). K=128 j-concat.
__global__ __launch_bounds__(256) void k3b_spec2(const unsigned int* __restrict__ c1p,
                                                 const unsigned short* __restrict__ w1cc,
                                                 unsigned int* __restrict__ oftp)
{
    __shared__ __align__(16) unsigned short As[16 * 128];
    __shared__ __align__(16) unsigned short Ws[2 * 64 * 128];
    const int t = threadIdx.x;
    int id = blockIdx.x;
    const int h = id & 1; id >>= 1;
    const int kv = id & 15; const int b = id >> 4;
    {
        const uint4* wg = (const uint4*)(w1cc + (size_t)(h * 16 + kv) * 16384);
        for (int k = t; k < 2048; k += 256) ((uint4*)Ws)[k] = wg[k];
    }
    for (int idx = t; idx < 512; idx += 256) {
        int pp = idx >> 5, j2 = (idx & 31) << 1;
        const unsigned* src = c1p + ((size_t)(b * 32 + h * 16 + pp) * 16 + kv) * 64;
        unsigned a0 = src[j2], a1 = src[j2 + 1];
        unsigned rep = (a0 & 0xffffu) | (a1 << 16);
        unsigned imp = (a0 >> 16) | (a1 & 0xffff0000u);
        int chr = j2 >> 3;
        *(unsigned*)&As[pp * 128 + SWZ128(pp, chr) + (j2 & 7)] = rep;
        int kk = 64 + j2;
        int chi = kk >> 3;
        *(unsigned*)&As[pp * 128 + SWZ128(pp, chi) + (kk & 7)] = imp;
    }
    __syncthreads();
    const int lane = t & 63, wv = t >> 6;
    const int ar = lane & 15, kg = lane >> 4;
    const int orow = wv * 16 + ar;
    f32x4 accre = (f32x4){0.f, 0.f, 0.f, 0.f};
    f32x4 accim = (f32x4){0.f, 0.f, 0.f, 0.f};
    #pragma unroll
    for (int ks = 0; ks < 4; ++ks) {
        int ch = ks * 4 + kg;
        bf16x8 af = *(const bf16x8*)&As[ar * 128 + SWZ128(ar, ch)];
        bf16x8 br = *(const bf16x8*)&Ws[orow * 128 + SWZ128(orow, ch)];
        bf16x8 bi = *(const bf16x8*)&Ws[8192 + orow * 128 + SWZ128(orow, ch)];
        accre = __builtin_amdgcn_mfma_f32_16x16x32_bf16(af, br, accre, 0, 0, 0);
        accim = __builtin_amdgcn_mfma_f32_16x16x32_bf16(af, bi, accim, 0, 0, 0);
    }
    #pragma unroll
    for (int r = 0; r < 4; ++r) {
        int pp = kg * 4 + r;
        oftp[((size_t)(b * 32 + h * 16 + pp) * 16 + kv) * 64 + orow] =
            (unsigned)f2bf(accre[r]) | ((unsigned)f2bf(accim[r]) << 16);
    }
}

// k4 (MFMA): T[u,o] = E*[re;im] per (b,q). K=64 concat.
__global__ __launch_bounds__(256) void k4_idft_m(const unsigned int* __restrict__ oftp,
                                                 const unsigned short* __restrict__ e2k4,
                                                 unsigned int* __restrict__ T)
{
    __shared__ __align__(16) unsigned short El[16384];
    __shared__ __align__(16) unsigned short Sl[4096];
    const int t = threadIdx.x;
    const int b = blockIdx.x >> 4, q = blockIdx.x & 15;
    {
        const uint4* eg = (const uint4*)e2k4;
        for (int k = t; k < 2048; k += 256) ((uint4*)El)[k] = eg[k];
    }
    for (int idx = t; idx < 1024; idx += 256) {
        int p2 = idx >> 6, o = idx & 63;
        int p = p2 << 1;
        unsigned a0 = oftp[((size_t)(b * 32 + p) * 16 + q) * 64 + o];
        unsigned a1 = oftp[((size_t)(b * 32 + p + 1) * 16 + q) * 64 + o];
        unsigned rep = (a0 & 0xffffu) | (a1 << 16);
        unsigned imp = (a0 >> 16) | (a1 & 0xffff0000u);
        int chr = p >> 3;
        *(unsigned*)&Sl[o * 64 + ((chr ^ (o & 7)) << 3) + (p & 7)] = rep;
        int kk = 32 + p;
        int chi = kk >> 3;
        *(unsigned*)&Sl[o * 64 + ((chi ^ (o & 7)) << 3) + (kk & 7)] = imp;
    }
    __syncthreads();
    const int lane = t & 63, wv = t >> 6;
    const int ar = lane & 15, kg = lane >> 4;
    unsigned int* Tp = T + ((size_t)b * 128) * 1024 + (size_t)q * 64;
    #pragma unroll
    for (int uti = 0; uti < 2; ++uti) {
        int ut = wv * 2 + uti;
        int urow = ut * 16 + ar;
        int aswz = urow & 7;
        #pragma unroll
        for (int ot = 0; ot < 4; ++ot) {
            int orow = ot * 16 + ar;
            f32x4 accre = (f32x4){0.f, 0.f, 0.f, 0.f};
            f32x4 accim = (f32x4){0.f, 0.f, 0.f, 0.f};
            #pragma unroll
            for (int ks = 0; ks < 2; ++ks) {
                int ch = ks * 4 + kg;
                int aoff = urow * 64 + ((ch ^ aswz) << 3);
                int boff = orow * 64 + ((ch ^ (orow & 7)) << 3);
                bf16x8 bfrag = *(const bf16x8*)&Sl[boff];
                bf16x8 fre = *(const bf16x8*)&El[aoff];
                bf16x8 fim = *(const bf16x8*)&El[8192 + aoff];
                accre = __builtin_amdgcn_mfma_f32_16x16x32_bf16(fre, bfrag, accre, 0, 0, 0);
                accim = __builtin_amdgcn_mfma_f32_16x16x32_bf16(fim, bfrag, accim, 0, 0, 0);
            }
            #pragma unroll
            for (int r = 0; r < 4; ++r) {
                int u = ut * 16 + kg * 4 + r;
                int o = ot * 16 + ar;
                Tp[(size_t)u * 1024 + o] =
                    (unsigned)f2bf(accre[r]) | ((unsigned)f2bf(accim[r]) << 16);
            }
        }
    }
}

// k56: 2 bm per block (grid 2048). LDS 80K -> 2 blocks/CU. 5 barriers. (= R12)
__global__ __launch_bounds__(256) void k56_fused(
    const float* __restrict__ x, const unsigned int* __restrict__ Tg,
    const float* __restrict__ bl,
    const unsigned short* __restrict__ ctb_pre, const unsigned short* __restrict__ wlt_pre,
    const unsigned short* __restrict__ w1bt, const unsigned short* __restrict__ w2bt,
    const float* __restrict__ bb1, const float* __restrict__ bb2,
    const float* __restrict__ bf1, const float* __restrict__ bf2,
    float* __restrict__ out)
{
    __shared__ __align__(16) unsigned char U[32768];
    __shared__ __align__(16) unsigned short ys[2][8192];
    __shared__ __align__(16) unsigned short hs[8192];

    unsigned short* Ctb = (unsigned short*)U;
    unsigned short* wlt = (unsigned short*)(U + 8192);
    unsigned short* Tpk = (unsigned short*)(U + 16384);
    unsigned short* w1s = (unsigned short*)U;
    unsigned short* w2s = (unsigned short*)(U + 16384);

    const int t = threadIdx.x;
    const int bm0 = blockIdx.x << 1;
    const int lane = t & 63, wv = t >> 6;
    const int ar = lane & 15, kg = lane >> 4;
    const int R0 = wv * 32;

    float4 xr[2][2][4];
    #pragma unroll
    for (int g = 0; g < 2; ++g)
        #pragma unroll
        for (int rt = 0; rt < 2; ++rt) {
            const float* xp = x + (size_t)(bm0 + g) * 8192 + (R0 + rt * 16 + ar) * 64 + kg * 8;
            xr[g][rt][0] = *(const float4*)(xp);
            xr[g][rt][1] = *(const float4*)(xp + 4);
            xr[g][rt][2] = *(const float4*)(xp + 32);
            xr[g][rt][3] = *(const float4*)(xp + 36);
        }

    {
        const uint4* cg = (const uint4*)ctb_pre;
        for (int k = t; k < 512; k += 256) ((uint4*)Ctb)[k] = cg[k];
        const uint4* wg = (const uint4*)wlt_pre;
        for (int k = t; k < 512; k += 256) ((uint4*)wlt)[k] = wg[k];
        for (int idx = t; idx < 2048; idx += 256) {
            int g = idx >> 10, rem = idx & 1023;
            int q = rem >> 6, o = rem & 63;
            unsigned v = Tg[(size_t)(bm0 + g) * 1024 + rem];
            int f = (o >> 1) & 3;
            unsigned short* Tp = Tpk + g * 2048;
            Tp[o * 32 + (((q >> 3) ^ f) << 3) + (q & 7)] = (unsigned short)(v & 0xffffu);
            Tp[o * 32 + (((2 + (q >> 3)) ^ f) << 3) + (q & 7)] = (unsigned short)(v >> 16);
        }
    }
    __syncthreads();   // B1

    float biasl[4];
    #pragma unroll
    for (int ct = 0; ct < 4; ++ct) biasl[ct] = bl[ct * 16 + ar];

    #pragma unroll
    for (int g = 0; g < 2; ++g) {
        const unsigned short* Tp = Tpk + g * 2048;
        #pragma unroll
        for (int rt = 0; rt < 2; ++rt) {
            const int vrow = R0 + rt * 16 + ar;
            bf16x8 a0 = cvt8(xr[g][rt][0], xr[g][rt][1]);
            bf16x8 a1 = cvt8(xr[g][rt][2], xr[g][rt][3]);
            bf16x8 asp = *(const bf16x8*)&Ctb[vrow * 32 + ((kg ^ ((vrow >> 1) & 3)) << 3)];
            f32x4 acc[4];
            #pragma unroll
            for (int ct = 0; ct < 4; ++ct) acc[ct] = (f32x4){0.f, 0.f, 0.f, 0.f};
            #pragma unroll
            for (int ct = 0; ct < 4; ++ct) {
                int o = ct * 16 + ar;
                bf16x8 b0 = *(const bf16x8*)&wlt[o * 64 + ((kg ^ (o & 7)) << 3)];
                bf16x8 b1 = *(const bf16x8*)&wlt[o * 64 + (((4 + kg) ^ (o & 7)) << 3)];
                bf16x8 bsp = *(const bf16x8*)&Tp[o * 32 + ((kg ^ ((o >> 1) & 3)) << 3)];
                acc[ct] = __builtin_amdgcn_mfma_f32_16x16x32_bf16(a0, b0, acc[ct], 0, 0, 0);
                acc[ct] = __builtin_amdgcn_mfma_f32_16x16x32_bf16(a1, b1, acc[ct], 0, 0, 0);
                acc[ct] = __builtin_amdgcn_mfma_f32_16x16x32_bf16(asp, bsp, acc[ct], 0, 0, 0);
            }
            #pragma unroll
            for (int ct = 0; ct < 4; ++ct) {
                int col = ct * 16 + ar;
                #pragma unroll
                for (int r = 0; r < 4; ++r) {
                    int row = R0 + rt * 16 + kg * 4 + r;
                    float v = fmaxf(acc[ct][r] + biasl[ct], 0.f);
                    ys[g][row * 64 + (((col >> 3) ^ (row & 7)) << 3) + (col & 7)] = f2bf(v);
                }
            }
        }
    }
    __syncthreads();   // B2

    unsigned short* hw = hs + wv * 2048;
    for (int head = 0; head < 2; ++head) {
        {
            const uint4* g1 = (const uint4*)(w1bt + head * 8192);
            for (int k = t; k < 1024; k += 256) ((uint4*)w1s)[k] = g1[k];
            const uint4* g2 = (const uint4*)(w2bt + head * 8192);
            for (int k = t; k < 1024; k += 256) ((uint4*)w2s)[k] = g2[k];
        }
        const float* B1 = head ? bf1 : bb1;
        const float* B2 = head ? bf2 : bb2;
        float bias1[8], bias2[4];
        #pragma unroll
        for (int c = 0; c < 8; ++c) bias1[c] = B1[c * 16 + ar];
        #pragma unroll
        for (int c = 0; c < 4; ++c) bias2[c] = B2[c * 16 + ar];
        __syncthreads();   // B3 / B5

        #pragma unroll
        for (int g = 0; g < 2; ++g) {
            #pragma unroll
            for (int rt = 0; rt < 2; ++rt) {
                const int rowbase = R0 + rt * 16;
                const int yrow = rowbase + ar;
                bf16x8 ya0 = *(const bf16x8*)&ys[g][yrow * 64 + ((kg ^ (yrow & 7)) << 3)];
                bf16x8 ya1 = *(const bf16x8*)&ys[g][yrow * 64 + (((4 + kg) ^ (yrow & 7)) << 3)];
                f32x4 acc1[8];
                #pragma unroll
                for (int ct = 0; ct < 8; ++ct) acc1[ct] = (f32x4){0.f, 0.f, 0.f, 0.f};
                #pragma unroll
                for (int ct = 0; ct < 8; ++ct) {
                    int brow = ct * 16 + ar;
                    bf16x8 b0 = *(const bf16x8*)&w1s[brow * 64 + ((kg ^ (brow & 7)) << 3)];
                    bf16x8 b1 = *(const bf16x8*)&w1s[brow * 64 + (((4 + kg) ^ (brow & 7)) << 3)];
                    acc1[ct] = __builtin_amdgcn_mfma_f32_16x16x32_bf16(ya0, b0, acc1[ct], 0, 0, 0);
                    acc1[ct] = __builtin_amdgcn_mfma_f32_16x16x32_bf16(ya1, b1, acc1[ct], 0, 0, 0);
                }
                #pragma unroll
                for (int ct = 0; ct < 8; ++ct) {
                    #pragma unroll
                    for (int r = 0; r < 4; ++r) {
                        int row = kg * 4 + r;
                        int col = ct * 16 + ar;
                        float v = fmaxf(acc1[ct][r] + bias1[ct], 0.f);
                        hw[row * 128 + (((col >> 3) ^ (row & 7)) << 3) + (col & 7)] = f2bf(v);
                    }
                }
                f32x4 acc2[4];
                #pragma unroll
                for (int ct = 0; ct < 4; ++ct) acc2[ct] = (f32x4){0.f, 0.f, 0.f, 0.f};
                #pragma unroll
                for (int ks = 0; ks < 4; ++ks) {
                    bf16x8 a = *(const bf16x8*)&hw[ar * 128 + (((ks * 4 + kg) ^ (ar & 7)) << 3)];
                    #pragma unroll
                    for (int ct = 0; ct < 4; ++ct) {
                        int brow = ct * 16 + ar;
                        bf16x8 b = *(const bf16x8*)&w2s[brow * 128 + (((ks * 4 + kg) ^ (ar & 7)) << 3)];
                        acc2[ct] = __builtin_amdgcn_mfma_f32_16x16x32_bf16(a, b, acc2[ct], 0, 0, 0);
                    }
                }
                float* og = out + (size_t)head * 33554432u + (size_t)(bm0 + g) * 8192;
                #pragma unroll
                for (int ct = 0; ct < 4; ++ct) {
                    #pragma unroll
                    for (int r = 0; r < 4; ++r)
                        og[(size_t)(rowbase + kg * 4 + r) * 64 + ct * 16 + ar] =
                            acc2[ct][r] + bias2[ct];
                }
            }
        }
        if (head == 0) __syncthreads();   // B4
    }
}

extern "C" void kernel_launch(void* const* d_in, const int* in_sizes, int n_in,
                              void* d_out, int out_size, void* d_ws, size_t ws_size,
                              hipStream_t stream)
{
    (void)in_sizes; (void)n_in; (void)out_size; (void)ws_size;
    const float* x   = (const float*)d_in[0];
    const float* ws0 = (const float*)d_in[1];
    const float* ws1 = (const float*)d_in[2];
    const float* wl  = (const float*)d_in[3];
    const float* bl  = (const float*)d_in[4];
    const float* wb1 = (const float*)d_in[5];
    const float* bb1 = (const float*)d_in[6];
    const float* wb2 = (const float*)d_in[7];
    const float* bb2 = (const float*)d_in[8];
    const float* wf1 = (const float*)d_in[9];
    const float* bf1 = (const float*)d_in[10];
    const float* wf2 = (const float*)d_in[11];
    const float* bf2 = (const float*)d_in[12];
    float* out = (float*)d_out;

    float* ws = (float*)d_ws;
    unsigned short* w0cc = (unsigned short*)ws;              // 524288 u16
    unsigned short* w1cc = (unsigned short*)(ws + 262144);   // 524288 u16
    unsigned int* Tb   = (unsigned int*)(ws + 524288);       // 4194304 u32
    unsigned int* Ab   = (unsigned int*)(ws + 8912896);      // 4194304 u32
    unsigned int* xftp = (unsigned int*)(ws + 17301504);     // 1048576 u32
    unsigned int* c1p  = (unsigned int*)(ws + 19398656);     // 1048576 u32
    unsigned int* oftp = (unsigned int*)(ws + 21495808);     // 1048576 u32
    unsigned short* w1bt    = (unsigned short*)(ws + 23592960);  // 16384 u16
    unsigned short* w2bt    = (unsigned short*)(ws + 23601152);  // 16384 u16
    unsigned short* wlt_pre = (unsigned short*)(ws + 23609344);  // 4096 u16
    unsigned short* ctb_pre = (unsigned short*)(ws + 23611392);  // 4096 u16
    unsigned short* wdft    = (unsigned short*)(ws + 23613440);  // 4352 u16
    unsigned short* e2k2    = (unsigned short*)(ws + 23615616);  // 16384 u16
    unsigned short* e2k4    = (unsigned short*)(ws + 23623808);  // 16384 u16

    k0_prep    <<<4096, 256, 0, stream>>>(ws0, ws1, w0cc, w1cc);
    k0b_prep   <<<305,  256, 0, stream>>>(wb1, wf1, wb2, wf2, wl,
                                          w1bt, w2bt, wlt_pre, ctb_pre, wdft,
                                          e2k2, e2k4);
    k1_dft_n   <<<4096, 256, 0, stream>>>(x, wdft, Ab);
    k2_dft_m   <<<512,  256, 0, stream>>>(Ab, e2k2, xftp);
    k3a_spec1  <<<1024, 256, 0, stream>>>(xftp, w0cc, c1p);
    k3b_spec2  <<<1024, 256, 0, stream>>>(c1p, w1cc, oftp);
    k4_idft_m  <<<512,  256, 0, stream>>>(oftp, e2k4, Tb);
    k56_fused  <<<2048, 256, 0, stream>>>(x, Tb, bl, ctb_pre, wlt_pre,
                                          w1bt, w2bt, bb1, bb2, bf1, bf2, out);
}

// Round 16
// 192.228 us; speedup vs baseline: 1.1509x; 1.0111x over previous
//
#include <hip/hip_runtime.h>
#include <hip/hip_bf16.h>

#define TWO_PI 6.28318530717958647692f

typedef __attribute__((ext_vector_type(8))) short bf16x8;
typedef __attribute__((ext_vector_type(4))) float f32x4;

__device__ __forceinline__ unsigned short f2bf(float v) {
    __hip_bfloat16 h = __float2bfloat16(v);
    return *(unsigned short*)&h;
}

__device__ __forceinline__ bf16x8 cvt8(float4 a, float4 b) {
    bf16x8 r;
    r[0] = (short)f2bf(a.x); r[1] = (short)f2bf(a.y);
    r[2] = (short)f2bf(a.z); r[3] = (short)f2bf(a.w);
    r[4] = (short)f2bf(b.x); r[5] = (short)f2bf(b.y);
    r[6] = (short)f2bf(b.z); r[7] = (short)f2bf(b.w);
    return r;
}

// 128-col swizzle helper (row stride 128 u16 = 256B, ch = k>>3 in 0..15):
//   slot = ((ch&8) | ((ch^row)&7)) << 3  |  (k&7)
#define SWZ128(row, ch) ((((ch) & 8) | (((ch) ^ ((row) & 7)) & 7)) << 3)

// Problem: B=32, M=N=128, I=O=64, NM=16.
// Spectral path keeps km in {0..15,112..127} (p=0..31), kn=0..15 (q).
// Spectral branch contributes ~1e-6 abs to y -> bf16 anywhere in it is free.
// A, T, xft, c1, oft are packed bf16 pairs (u32: re low, im high).
//
// Session log: R5 MFMA operands from LDS/regs only. R9 k1->MFMA. R10 k56
// 2-bm/block. R11 k2/k4->MFMA (K-concat complex split). R12 k3a/k3b->MFMA.
// BEST = 191us (R12); R13 split / R14 reg-preload / R7 global-operand all
// regressed and are reverted. Final state = R12.
//
// ws layout (float offsets):
//   w0cc    @ 0        : 524288 u16 [p:32][2][j:64][k:128] bf16 swz
//   w1cc    @ 262144   : 524288 u16 [hkv:32][2][o:64][k:128] bf16 swz
//   T       @ 524288   : 4194304 u32 packed bf16 (b,u,q,o)
//   A       @ 8912896  : 4194304 u32 packed bf16 (b,m,kv,i)
//   xft     @ 17301504 : 1048576 u32 packed (b,p,kv,i)
//   c1      @ 19398656 : 1048576 u32 packed (b,p,kv,j)
//   oft     @ 21495808 : 1048576 u32 packed (b,p,kv,o)
//   w1bt    @ 23592960 : 16384 u16  W1t[2][o:128][k:64] bf16 PRE-SWIZZLED
//   w2bt    @ 23601152 : 16384 u16  W2t[2][o:64][k:128] bf16 PRE-SWIZZLED
//   wlt_pre @ 23609344 : 4096 u16   w_lin^T bf16 pre-swizzled
//   ctb_pre @ 23611392 : 4096 u16   irfft coeff bf16 pre-swizzled
//   wdft    @ 23613440 : 4352 u16   DFT matrix [c:2][kv:16][n:136 pad] bf16
//   e2k2    @ 23615616 : 16384 u16  k2 E [2][p:32][k:256] bf16 swz, 1/128 folded
//   e2k4    @ 23623808 : 16384 u16  k4 E [2][u:128][k:64] bf16 swz

// k0: K-concat bf16 pre-swizzled spectral weights.
__global__ __launch_bounds__(256) void k0_prep(const float* __restrict__ ws0,
                                               const float* __restrict__ ws1,
                                               unsigned short* __restrict__ w0cc,
                                               unsigned short* __restrict__ w1cc)
{
    int tgt = blockIdx.x * 256 + threadIdx.x;   // 0..1048575
    int which = tgt >> 19;
    int u = tgt & 524287;
    int ps = u >> 14;          // p (w0cc) or h*16+kv (w1cc)
    int plane = (u >> 13) & 1;
    int row = (u >> 7) & 63;   // j or o
    int k = u & 127;
    int half = k >> 6, e = k & 63;
    float re, im;
    if (which == 0) {
        const float* s = (ps < 16) ? ws0 : ws1;          // f=0 plane
        int base = ((e * 64 + row) * 16 + (ps & 15)) * 2; // i=e, j=row
        re = s[base]; im = s[base + 1];
    } else {
        const float* s = ((ps >> 4) ? ws1 : ws0) + 131072; // f=1 plane
        int base = ((e * 64 + row) * 16 + (ps & 15)) * 2;  // j=e, o=row
        re = s[base]; im = s[base + 1];
    }
    float val = plane ? (half ? re : im) : (half ? -im : re);
    int ch = k >> 3;
    int dst = ps * 16384 + plane * 8192 + row * 128 + SWZ128(row, ch) + (k & 7);
    (which ? w1cc : w0cc)[dst] = f2bf(val);
}

// weights + tables (pre-swizzled where consumed from LDS)
__global__ __launch_bounds__(256) void k0b_prep(const float* __restrict__ wb1,
                                                const float* __restrict__ wf1,
                                                const float* __restrict__ wb2,
                                                const float* __restrict__ wf2,
                                                const float* __restrict__ wl,
                                                unsigned short* __restrict__ w1bt,
                                                unsigned short* __restrict__ w2bt,
                                                unsigned short* __restrict__ wlt_pre,
                                                unsigned short* __restrict__ ctb_pre,
                                                unsigned short* __restrict__ wdft,
                                                unsigned short* __restrict__ e2k2,
                                                unsigned short* __restrict__ e2k4)
{
    int tgt = blockIdx.x * 256 + threadIdx.x;   // 0..78079
    if (tgt < 16384) {
        int head = tgt >> 13;
        int o = (tgt >> 6) & 127;
        int i = tgt & 63;
        const float* src = head ? wf1 : wb1;    // [64][128]
        int dst = head * 8192 + o * 64 + (((i >> 3) ^ (o & 7)) << 3) + (i & 7);
        w1bt[dst] = f2bf(src[i * 128 + o]);
    } else if (tgt < 32768) {
        int u = tgt - 16384;
        int head = u >> 13;
        int o = (u >> 7) & 63;
        int c = u & 127;
        const float* src = head ? wf2 : wb2;    // [128][64]
        int dst = head * 8192 + o * 128 + (((c >> 3) ^ (o & 7)) << 3) + (c & 7);
        w2bt[dst] = f2bf(src[c * 64 + o]);
    } else if (tgt < 36864) {
        int u = tgt - 32768;                    // 0..4095
        int o = u >> 6, i = u & 63;
        int chunk = (i >> 3) ^ (o & 7);
        wlt_pre[o * 64 + chunk * 8 + (i & 7)] = f2bf(wl[i * 64 + o]);
    } else if (tgt < 40960) {
        int u = tgt - 36864;                    // 0..4095
        int v = u >> 5, k = u & 31;             // v 0..127, k 0..31
        float val;
        if (k < 16) {
            val = (k == 0) ? (1.0f / 128.0f)
                           : (2.0f / 128.0f) * cosf(TWO_PI * k * v * (1.0f / 128.0f));
        } else {
            int q = k - 16;
            val = (q == 0) ? 0.f
                           : -(2.0f / 128.0f) * sinf(TWO_PI * q * v * (1.0f / 128.0f));
        }
        int chunk = (k >> 3) ^ ((v >> 1) & 3);
        ctb_pre[v * 32 + chunk * 8 + (k & 7)] = f2bf(val);
    } else if (tgt < 45312) {
        int u = tgt - 40960;                    // 0..4351
        int c = u / 2176;
        int rem = u - c * 2176;
        int kv = rem / 136, n = rem - (rem / 136) * 136;
        float val = 0.f;
        if (n < 128) {
            int idx = (kv * n) & 127;
            float th = (float)idx * (TWO_PI / 128.0f);
            val = c ? -sinf(th) : cosf(th);
        }
        wdft[u] = f2bf(val);
    } else if (tgt < 61696) {
        // k2 E: [plane:2][p:32][k:256] swz; plane0=[c|s]/128, plane1=[-s|c]/128
        int u = tgt - 45312;
        int plane = u >> 13;
        int rem = u & 8191;
        int p = rem >> 8;
        int k = rem & 255;
        int km = (p < 16) ? p : (96 + p);
        int m = (k < 128) ? k : (k - 128);
        float th = (float)((km * m) & 127) * (TWO_PI / 128.0f);
        float c = cosf(th), s = sinf(th);
        float val = plane ? ((k < 128) ? -s : c) : ((k < 128) ? c : s);
        val *= (1.0f / 128.0f);
        int ch = k >> 3;
        int dst = plane * 8192 + p * 256 + (((ch & 24) | ((ch ^ p) & 7)) << 3) + (k & 7);
        e2k2[dst] = f2bf(val);
    } else {
        // k4 E: [plane:2][u:128][k:64] swz; plane0=[c|-s], plane1=[s|c]
        int u = tgt - 61696;
        int plane = u >> 13;
        int rem = u & 8191;
        int uu = rem >> 6;
        int k = rem & 63;
        int p = (k < 32) ? k : (k - 32);
        int km = (p < 16) ? p : (96 + p);
        float th = (float)((km * uu) & 127) * (TWO_PI / 128.0f);
        float c = cosf(th), s = sinf(th);
        float val = plane ? ((k < 32) ? s : c) : ((k < 32) ? c : -s);
        int ch = k >> 3;
        int dst = plane * 8192 + uu * 64 + (((ch ^ (uu & 7)) & 7) << 3) + (k & 7);
        e2k4[dst] = f2bf(val);
    }
}

// k1 (MFMA): A[b,m,kv,i] = sum_n W[kv,n] x[b,m,n,i], packed bf16 u32 out.
__global__ __launch_bounds__(256) void k1_dft_n(const float* __restrict__ x,
                                                const unsigned short* __restrict__ wdft,
                                                unsigned int* __restrict__ A)
{
    __shared__ __align__(16) unsigned short Xt[64 * 136];    // 17408 B
    __shared__ __align__(16) unsigned short Wl[2 * 16 * 136];//  8704 B
    const int t = threadIdx.x;
    const int bm = blockIdx.x;
    {
        const uint4* wg = (const uint4*)wdft;
        uint4* wl = (uint4*)Wl;
        for (int k = t; k < 544; k += 256) wl[k] = wg[k];
    }
    {
        const float* xg = x + (size_t)bm * 8192;
        const int i = t & 63, q = t >> 6;
        #pragma unroll
        for (int pass = 0; pass < 8; ++pass) {
            int n0 = pass * 16 + q * 4;
            float v0 = xg[(n0 + 0) * 64 + i];
            float v1 = xg[(n0 + 1) * 64 + i];
            float v2 = xg[(n0 + 2) * 64 + i];
            float v3 = xg[(n0 + 3) * 64 + i];
            unsigned lo = (unsigned)f2bf(v0) | ((unsigned)f2bf(v1) << 16);
            unsigned hi = (unsigned)f2bf(v2) | ((unsigned)f2bf(v3) << 16);
            *(uint2*)&Xt[i * 136 + n0] = make_uint2(lo, hi);
        }
    }
    __syncthreads();
    const int lane = t & 63, wv = t >> 6;
    const int ar = lane & 15, kg = lane >> 4;
    f32x4 are = (f32x4){0.f, 0.f, 0.f, 0.f};
    f32x4 aim = (f32x4){0.f, 0.f, 0.f, 0.f};
    #pragma unroll
    for (int ks = 0; ks < 4; ++ks) {
        int off = ks * 32 + kg * 8;
        bf16x8 b   = *(const bf16x8*)&Xt[(wv * 16 + ar) * 136 + off];
        bf16x8 wre = *(const bf16x8*)&Wl[ar * 136 + off];
        bf16x8 wim = *(const bf16x8*)&Wl[(16 + ar) * 136 + off];
        are = __builtin_amdgcn_mfma_f32_16x16x32_bf16(wre, b, are, 0, 0, 0);
        aim = __builtin_amdgcn_mfma_f32_16x16x32_bf16(wim, b, aim, 0, 0, 0);
    }
    unsigned int* Ap = A + (size_t)bm * 1024;
    #pragma unroll
    for (int r = 0; r < 4; ++r) {
        int kv = kg * 4 + r;
        int i = wv * 16 + ar;
        Ap[kv * 64 + i] = (unsigned)f2bf(are[r]) | ((unsigned)f2bf(aim[r]) << 16);
    }
}

// k2 (MFMA): xft[p,i] = E*[ar;ai] per (b,kv). K=256 concat. Packed u32 out.
__global__ __launch_bounds__(256) void k2_dft_m(const unsigned int* __restrict__ A,
                                                const unsigned short* __restrict__ e2k2,
                                                unsigned int* __restrict__ xftp)
{
    __shared__ __align__(16) unsigned short El[16384];  // [2][32][256] swz, 32KB
    __shared__ __align__(16) unsigned short Sl[16384];  // [i:64][k:256] swz, 32KB
    const int t = threadIdx.x;
    const int b = blockIdx.x >> 4, kv = blockIdx.x & 15;
    {
        const uint4* eg = (const uint4*)e2k2;
        for (int k = t; k < 2048; k += 256) ((uint4*)El)[k] = eg[k];
    }
    for (int idx = t; idx < 4096; idx += 256) {
        int m2 = idx >> 6, i = idx & 63;
        int m = m2 << 1;
        unsigned a0 = A[((size_t)(b * 128 + m) * 16 + kv) * 64 + i];
        unsigned a1 = A[((size_t)(b * 128 + m + 1) * 16 + kv) * 64 + i];
        unsigned arp = (a0 & 0xffffu) | (a1 << 16);
        unsigned aip = (a0 >> 16) | (a1 & 0xffff0000u);
        int chr = m >> 3;
        *(unsigned*)&Sl[i * 256 + (((chr & 24) | ((chr ^ i) & 7)) << 3) + (m & 7)] = arp;
        int kk = 128 + m;
        int chi = kk >> 3;
        *(unsigned*)&Sl[i * 256 + (((chi & 24) | ((chi ^ i) & 7)) << 3) + (kk & 7)] = aip;
    }
    __syncthreads();
    const int lane = t & 63, wv = t >> 6;
    const int ar = lane & 15, kg = lane >> 4;
    const int pt = wv >> 1;
    const int it0 = (wv & 1) << 1;
    #pragma unroll
    for (int iti = 0; iti < 2; ++iti) {
        int it = it0 + iti;
        int prow = pt * 16 + ar;
        int irow = it * 16 + ar;
        f32x4 accre = (f32x4){0.f, 0.f, 0.f, 0.f};
        f32x4 accim = (f32x4){0.f, 0.f, 0.f, 0.f};
        #pragma unroll
        for (int ks = 0; ks < 8; ++ks) {
            int ch = ks * 4 + kg;
            int aoff = prow * 256 + (((ch & 24) | ((ch ^ prow) & 7)) << 3);
            int boff = irow * 256 + (((ch & 24) | ((ch ^ irow) & 7)) << 3);
            bf16x8 bfrag = *(const bf16x8*)&Sl[boff];
            bf16x8 fre = *(const bf16x8*)&El[aoff];
            bf16x8 fim = *(const bf16x8*)&El[8192 + aoff];
            accre = __builtin_amdgcn_mfma_f32_16x16x32_bf16(fre, bfrag, accre, 0, 0, 0);
            accim = __builtin_amdgcn_mfma_f32_16x16x32_bf16(fim, bfrag, accim, 0, 0, 0);
        }
        #pragma unroll
        for (int r = 0; r < 4; ++r) {
            int p = pt * 16 + kg * 4 + r;
            int i = it * 16 + ar;
            xftp[((size_t)(b * 32 + p) * 16 + kv) * 64 + i] =
                (unsigned)f2bf(accre[r]) | ((unsigned)f2bf(accim[r]) << 16);
        }
    }
}

// k3a (MFMA): c1[kv,j] = xft[kv,:] @ w0cc[p] per (b,p). K=128 i-concat.
__global__ __launch_bounds__(256) void k3a_spec1(const unsigned int* __restrict__ xftp,
                                                 const unsigned short* __restrict__ w0cc,
                                                 unsigned int* __restrict__ c1p)
{
    __shared__ __align__(16) unsigned short As[16 * 128];
    __shared__ __align__(16) unsigned short Ws[2 * 64 * 128];
    const int t = threadIdx.x;
    const int b = blockIdx.x >> 5, p = blockIdx.x & 31;
    {
        const uint4* wg = (const uint4*)(w0cc + (size_t)p * 16384);
        for (int k = t; k < 2048; k += 256) ((uint4*)Ws)[k] = wg[k];
    }
    for (int idx = t; idx < 512; idx += 256) {
        int kvv = idx >> 5, i2 = (idx & 31) << 1;
        const unsigned* src = xftp + ((size_t)(b * 32 + p) * 16 + kvv) * 64;
        unsigned a0 = src[i2], a1 = src[i2 + 1];
        unsigned rep = (a0 & 0xffffu) | (a1 << 16);
        unsigned imp = (a0 >> 16) | (a1 & 0xffff0000u);
        int chr = i2 >> 3;
        *(unsigned*)&As[kvv * 128 + SWZ128(kvv, chr) + (i2 & 7)] = rep;
        int kk = 64 + i2;
        int chi = kk >> 3;
        *(unsigned*)&As[kvv * 128 + SWZ128(kvv, chi) + (kk & 7)] = imp;
    }
    __syncthreads();
    const int lane = t & 63, wv = t >> 6;
    const int ar = lane & 15, kg = lane >> 4;
    const int jrow = wv * 16 + ar;
    f32x4 accre = (f32x4){0.f, 0.f, 0.f, 0.f};
    f32x4 accim = (f32x4){0.f, 0.f, 0.f, 0.f};
    #pragma unroll
    for (int ks = 0; ks < 4; ++ks) {
        int ch = ks * 4 + kg;
        bf16x8 af = *(const bf16x8*)&As[ar * 128 + SWZ128(ar, ch)];
        bf16x8 br = *(const bf16x8*)&Ws[jrow * 128 + SWZ128(jrow, ch)];
        bf16x8 bi = *(const bf16x8*)&Ws[8192 + jrow * 128 + SWZ128(jrow, ch)];
        accre = __builtin_amdgcn_mfma_f32_16x16x32_bf16(af, br, accre, 0, 0, 0);
        accim = __builtin_amdgcn_mfma_f32_16x16x32_bf16(af, bi, accim, 0, 0, 0);
    }
    unsigned int* cp = c1p + ((size_t)(b * 32 + p) * 16) * 64;
    #pragma unroll
    for (int r = 0; r < 4; ++r) {
        int kv = kg * 4 + r;
        cp[kv * 64 + wv * 16 + ar] =
            (unsigned)f2bf(accre[r]) | ((unsigned)f2bf(accim[r]) << 16);
    }
}

// k3b (MFMA): oft[pp,o] = c1[pp,:] @ w1cc[h*16+kv] per (b,h,kv). K=128 j-concat.
__global__ __launch_bounds__(256) void k3b_spec2(const unsigned int* __restrict__ c1p,
                                                 const unsigned short* __restrict__ w1cc,
                                                 unsigned int* __restrict__ oftp)
{
    __shared__ __align__(16) unsigned short As[16 * 128];
    __shared__ __align__(16) unsigned short Ws[2 * 64 * 128];
    const int t = threadIdx.x;
    int id = blockIdx.x;
    const int h = id & 1; id >>= 1;
    const int kv = id & 15; const int b = id >> 4;
    {
        const uint4* wg = (const uint4*)(w1cc + (size_t)(h * 16 + kv) * 16384);
        for (int k = t; k < 2048; k += 256) ((uint4*)Ws)[k] = wg[k];
    }
    for (int idx = t; idx < 512; idx += 256) {
        int pp = idx >> 5, j2 = (idx & 31) << 1;
        const unsigned* src = c1p + ((size_t)(b * 32 + h * 16 + pp) * 16 + kv) * 64;
        unsigned a0 = src[j2], a1 = src[j2 + 1];
        unsigned rep = (a0 & 0xffffu) | (a1 << 16);
        unsigned imp = (a0 >> 16) | (a1 & 0xffff0000u);
        int chr = j2 >> 3;
        *(unsigned*)&As[pp * 128 + SWZ128(pp, chr) + (j2 & 7)] = rep;
        int kk = 64 + j2;
        int chi = kk >> 3;
        *(unsigned*)&As[pp * 128 + SWZ128(pp, chi) + (kk & 7)] = imp;
    }
    __syncthreads();
    const int lane = t & 63, wv = t >> 6;
    const int ar = lane & 15, kg = lane >> 4;
    const int orow = wv * 16 + ar;
    f32x4 accre = (f32x4){0.f, 0.f, 0.f, 0.f};
    f32x4 accim = (f32x4){0.f, 0.f, 0.f, 0.f};
    #pragma unroll
    for (int ks = 0; ks < 4; ++ks) {
        int ch = ks * 4 + kg;
        bf16x8 af = *(const bf16x8*)&As[ar * 128 + SWZ128(ar, ch)];
        bf16x8 br = *(const bf16x8*)&Ws[orow * 128 + SWZ128(orow, ch)];
        bf16x8 bi = *(const bf16x8*)&Ws[8192 + orow * 128 + SWZ128(orow, ch)];
        accre = __builtin_amdgcn_mfma_f32_16x16x32_bf16(af, br, accre, 0, 0, 0);
        accim = __builtin_amdgcn_mfma_f32_16x16x32_bf16(af, bi, accim, 0, 0, 0);
    }
    #pragma unroll
    for (int r = 0; r < 4; ++r) {
        int pp = kg * 4 + r;
        oftp[((size_t)(b * 32 + h * 16 + pp) * 16 + kv) * 64 + orow] =
            (unsigned)f2bf(accre[r]) | ((unsigned)f2bf(accim[r]) << 16);
    }
}

// k4 (MFMA): T[u,o] = E*[re;im] per (b,q). K=64 concat.
__global__ __launch_bounds__(256) void k4_idft_m(const unsigned int* __restrict__ oftp,
                                                 const unsigned short* __restrict__ e2k4,
                                                 unsigned int* __restrict__ T)
{
    __shared__ __align__(16) unsigned short El[16384];
    __shared__ __align__(16) unsigned short Sl[4096];
    const int t = threadIdx.x;
    const int b = blockIdx.x >> 4, q = blockIdx.x & 15;
    {
        const uint4* eg = (const uint4*)e2k4;
        for (int k = t; k < 2048; k += 256) ((uint4*)El)[k] = eg[k];
    }
    for (int idx = t; idx < 1024; idx += 256) {
        int p2 = idx >> 6, o = idx & 63;
        int p = p2 << 1;
        unsigned a0 = oftp[((size_t)(b * 32 + p) * 16 + q) * 64 + o];
        unsigned a1 = oftp[((size_t)(b * 32 + p + 1) * 16 + q) * 64 + o];
        unsigned rep = (a0 & 0xffffu) | (a1 << 16);
        unsigned imp = (a0 >> 16) | (a1 & 0xffff0000u);
        int chr = p >> 3;
        *(unsigned*)&Sl[o * 64 + ((chr ^ (o & 7)) << 3) + (p & 7)] = rep;
        int kk = 32 + p;
        int chi = kk >> 3;
        *(unsigned*)&Sl[o * 64 + ((chi ^ (o & 7)) << 3) + (kk & 7)] = imp;
    }
    __syncthreads();
    const int lane = t & 63, wv = t >> 6;
    const int ar = lane & 15, kg = lane >> 4;
    unsigned int* Tp = T + ((size_t)b * 128) * 1024 + (size_t)q * 64;
    #pragma unroll
    for (int uti = 0; uti < 2; ++uti) {
        int ut = wv * 2 + uti;
        int urow = ut * 16 + ar;
        int aswz = urow & 7;
        #pragma unroll
        for (int ot = 0; ot < 4; ++ot) {
            int orow = ot * 16 + ar;
            f32x4 accre = (f32x4){0.f, 0.f, 0.f, 0.f};
            f32x4 accim = (f32x4){0.f, 0.f, 0.f, 0.f};
            #pragma unroll
            for (int ks = 0; ks < 2; ++ks) {
                int ch = ks * 4 + kg;
                int aoff = urow * 64 + ((ch ^ aswz) << 3);
                int boff = orow * 64 + ((ch ^ (orow & 7)) << 3);
                bf16x8 bfrag = *(const bf16x8*)&Sl[boff];
                bf16x8 fre = *(const bf16x8*)&El[aoff];
                bf16x8 fim = *(const bf16x8*)&El[8192 + aoff];
                accre = __builtin_amdgcn_mfma_f32_16x16x32_bf16(fre, bfrag, accre, 0, 0, 0);
                accim = __builtin_amdgcn_mfma_f32_16x16x32_bf16(fim, bfrag, accim, 0, 0, 0);
            }
            #pragma unroll
            for (int r = 0; r < 4; ++r) {
                int u = ut * 16 + kg * 4 + r;
                int o = ot * 16 + ar;
                Tp[(size_t)u * 1024 + o] =
                    (unsigned)f2bf(accre[r]) | ((unsigned)f2bf(accim[r]) << 16);
            }
        }
    }
}

// k56: 2 bm per block (grid 2048). LDS 80K -> 2 blocks/CU. 5 barriers.
__global__ __launch_bounds__(256) void k56_fused(
    const float* __restrict__ x, const unsigned int* __restrict__ Tg,
    const float* __restrict__ bl,
    const unsigned short* __restrict__ ctb_pre, const unsigned short* __restrict__ wlt_pre,
    const unsigned short* __restrict__ w1bt, const unsigned short* __restrict__ w2bt,
    const float* __restrict__ bb1, const float* __restrict__ bb2,
    const float* __restrict__ bf1, const float* __restrict__ bf2,
    float* __restrict__ out)
{
    __shared__ __align__(16) unsigned char U[32768];
    __shared__ __align__(16) unsigned short ys[2][8192];
    __shared__ __align__(16) unsigned short hs[8192];

    unsigned short* Ctb = (unsigned short*)U;
    unsigned short* wlt = (unsigned short*)(U + 8192);
    unsigned short* Tpk = (unsigned short*)(U + 16384);
    unsigned short* w1s = (unsigned short*)U;
    unsigned short* w2s = (unsigned short*)(U + 16384);

    const int t = threadIdx.x;
    const int bm0 = blockIdx.x << 1;
    const int lane = t & 63, wv = t >> 6;
    const int ar = lane & 15, kg = lane >> 4;
    const int R0 = wv * 32;

    float4 xr[2][2][4];
    #pragma unroll
    for (int g = 0; g < 2; ++g)
        #pragma unroll
        for (int rt = 0; rt < 2; ++rt) {
            const float* xp = x + (size_t)(bm0 + g) * 8192 + (R0 + rt * 16 + ar) * 64 + kg * 8;
            xr[g][rt][0] = *(const float4*)(xp);
            xr[g][rt][1] = *(const float4*)(xp + 4);
            xr[g][rt][2] = *(const float4*)(xp + 32);
            xr[g][rt][3] = *(const float4*)(xp + 36);
        }

    {
        const uint4* cg = (const uint4*)ctb_pre;
        for (int k = t; k < 512; k += 256) ((uint4*)Ctb)[k] = cg[k];
        const uint4* wg = (const uint4*)wlt_pre;
        for (int k = t; k < 512; k += 256) ((uint4*)wlt)[k] = wg[k];
        for (int idx = t; idx < 2048; idx += 256) {
            int g = idx >> 10, rem = idx & 1023;
            int q = rem >> 6, o = rem & 63;
            unsigned v = Tg[(size_t)(bm0 + g) * 1024 + rem];
            int f = (o >> 1) & 3;
            unsigned short* Tp = Tpk + g * 2048;
            Tp[o * 32 + (((q >> 3) ^ f) << 3) + (q & 7)] = (unsigned short)(v & 0xffffu);
            Tp[o * 32 + (((2 + (q >> 3)) ^ f) << 3) + (q & 7)] = (unsigned short)(v >> 16);
        }
    }
    __syncthreads();   // B1

    float biasl[4];
    #pragma unroll
    for (int ct = 0; ct < 4; ++ct) biasl[ct] = bl[ct * 16 + ar];

    #pragma unroll
    for (int g = 0; g < 2; ++g) {
        const unsigned short* Tp = Tpk + g * 2048;
        #pragma unroll
        for (int rt = 0; rt < 2; ++rt) {
            const int vrow = R0 + rt * 16 + ar;
            bf16x8 a0 = cvt8(xr[g][rt][0], xr[g][rt][1]);
            bf16x8 a1 = cvt8(xr[g][rt][2], xr[g][rt][3]);
            bf16x8 asp = *(const bf16x8*)&Ctb[vrow * 32 + ((kg ^ ((vrow >> 1) & 3)) << 3)];
            f32x4 acc[4];
            #pragma unroll
            for (int ct = 0; ct < 4; ++ct) acc[ct] = (f32x4){0.f, 0.f, 0.f, 0.f};
            #pragma unroll
            for (int ct = 0; ct < 4; ++ct) {
                int o = ct * 16 + ar;
                bf16x8 b0 = *(const bf16x8*)&wlt[o * 64 + ((kg ^ (o & 7)) << 3)];
                bf16x8 b1 = *(const bf16x8*)&wlt[o * 64 + (((4 + kg) ^ (o & 7)) << 3)];
                bf16x8 bsp = *(const bf16x8*)&Tp[o * 32 + ((kg ^ ((o >> 1) & 3)) << 3)];
                acc[ct] = __builtin_amdgcn_mfma_f32_16x16x32_bf16(a0, b0, acc[ct], 0, 0, 0);
                acc[ct] = __builtin_amdgcn_mfma_f32_16x16x32_bf16(a1, b1, acc[ct], 0, 0, 0);
                acc[ct] = __builtin_amdgcn_mfma_f32_16x16x32_bf16(asp, bsp, acc[ct], 0, 0, 0);
            }
            #pragma unroll
            for (int ct = 0; ct < 4; ++ct) {
                int col = ct * 16 + ar;
                #pragma unroll
                for (int r = 0; r < 4; ++r) {
                    int row = R0 + rt * 16 + kg * 4 + r;
                    float v = fmaxf(acc[ct][r] + biasl[ct], 0.f);
                    ys[g][row * 64 + (((col >> 3) ^ (row & 7)) << 3) + (col & 7)] = f2bf(v);
                }
            }
        }
    }
    __syncthreads();   // B2

    unsigned short* hw = hs + wv * 2048;
    for (int head = 0; head < 2; ++head) {
        {
            const uint4* g1 = (const uint4*)(w1bt + head * 8192);
            for (int k = t; k < 1024; k += 256) ((uint4*)w1s)[k] = g1[k];
            const uint4* g2 = (const uint4*)(w2bt + head * 8192);
            for (int k = t; k < 1024; k += 256) ((uint4*)w2s)[k] = g2[k];
        }
        const float* B1 = head ? bf1 : bb1;
        const float* B2 = head ? bf2 : bb2;
        float bias1[8], bias2[4];
        #pragma unroll
        for (int c = 0; c < 8; ++c) bias1[c] = B1[c * 16 + ar];
        #pragma unroll
        for (int c = 0; c < 4; ++c) bias2[c] = B2[c * 16 + ar];
        __syncthreads();   // B3 / B5

        #pragma unroll
        for (int g = 0; g < 2; ++g) {
            #pragma unroll
            for (int rt = 0; rt < 2; ++rt) {
                const int rowbase = R0 + rt * 16;
                const int yrow = rowbase + ar;
                bf16x8 ya0 = *(const bf16x8*)&ys[g][yrow * 64 + ((kg ^ (yrow & 7)) << 3)];
                bf16x8 ya1 = *(const bf16x8*)&ys[g][yrow * 64 + (((4 + kg) ^ (yrow & 7)) << 3)];
                f32x4 acc1[8];
                #pragma unroll
                for (int ct = 0; ct < 8; ++ct) acc1[ct] = (f32x4){0.f, 0.f, 0.f, 0.f};
                #pragma unroll
                for (int ct = 0; ct < 8; ++ct) {
                    int brow = ct * 16 + ar;
                    bf16x8 b0 = *(const bf16x8*)&w1s[brow * 64 + ((kg ^ (brow & 7)) << 3)];
                    bf16x8 b1 = *(const bf16x8*)&w1s[brow * 64 + (((4 + kg) ^ (brow & 7)) << 3)];
                    acc1[ct] = __builtin_amdgcn_mfma_f32_16x16x32_bf16(ya0, b0, acc1[ct], 0, 0, 0);
                    acc1[ct] = __builtin_amdgcn_mfma_f32_16x16x32_bf16(ya1, b1, acc1[ct], 0, 0, 0);
                }
                #pragma unroll
                for (int ct = 0; ct < 8; ++ct) {
                    #pragma unroll
                    for (int r = 0; r < 4; ++r) {
                        int row = kg * 4 + r;
                        int col = ct * 16 + ar;
                        float v = fmaxf(acc1[ct][r] + bias1[ct], 0.f);
                        hw[row * 128 + (((col >> 3) ^ (row & 7)) << 3) + (col & 7)] = f2bf(v);
                    }
                }
                f32x4 acc2[4];
                #pragma unroll
                for (int ct = 0; ct < 4; ++ct) acc2[ct] = (f32x4){0.f, 0.f, 0.f, 0.f};
                #pragma unroll
                for (int ks = 0; ks < 4; ++ks) {
                    bf16x8 a = *(const bf16x8*)&hw[ar * 128 + (((ks * 4 + kg) ^ (ar & 7)) << 3)];
                    #pragma unroll
                    for (int ct = 0; ct < 4; ++ct) {
                        int brow = ct * 16 + ar;
                        bf16x8 b = *(const bf16x8*)&w2s[brow * 128 + (((ks * 4 + kg) ^ (ar & 7)) << 3)];
                        acc2[ct] = __builtin_amdgcn_mfma_f32_16x16x32_bf16(a, b, acc2[ct], 0, 0, 0);
                    }
                }
                float* og = out + (size_t)head * 33554432u + (size_t)(bm0 + g) * 8192;
                #pragma unroll
                for (int ct = 0; ct < 4; ++ct) {
                    #pragma unroll
                    for (int r = 0; r < 4; ++r)
                        og[(size_t)(rowbase + kg * 4 + r) * 64 + ct * 16 + ar] =
                            acc2[ct][r] + bias2[ct];
                }
            }
        }
        if (head == 0) __syncthreads();   // B4
    }
}

extern "C" void kernel_launch(void* const* d_in, const int* in_sizes, int n_in,
                              void* d_out, int out_size, void* d_ws, size_t ws_size,
                              hipStream_t stream)
{
    (void)in_sizes; (void)n_in; (void)out_size; (void)ws_size;
    const float* x   = (const float*)d_in[0];
    const float* ws0 = (const float*)d_in[1];
    const float* ws1 = (const float*)d_in[2];
    const float* wl  = (const float*)d_in[3];
    const float* bl  = (const float*)d_in[4];
    const float* wb1 = (const float*)d_in[5];
    const float* bb1 = (const float*)d_in[6];
    const float* wb2 = (const float*)d_in[7];
    const float* bb2 = (const float*)d_in[8];
    const float* wf1 = (const float*)d_in[9];
    const float* bf1 = (const float*)d_in[10];
    const float* wf2 = (const float*)d_in[11];
    const float* bf2 = (const float*)d_in[12];
    float* out = (float*)d_out;

    float* ws = (float*)d_ws;
    unsigned short* w0cc = (unsigned short*)ws;              // 524288 u16
    unsigned short* w1cc = (unsigned short*)(ws + 262144);   // 524288 u16
    unsigned int* Tb   = (unsigned int*)(ws + 524288);       // 4194304 u32
    unsigned int* Ab   = (unsigned int*)(ws + 8912896);      // 4194304 u32
    unsigned int* xftp = (unsigned int*)(ws + 17301504);     // 1048576 u32
    unsigned int* c1p  = (unsigned int*)(ws + 19398656);     // 1048576 u32
    unsigned int* oftp = (unsigned int*)(ws + 21495808);     // 1048576 u32
    unsigned short* w1bt    = (unsigned short*)(ws + 23592960);  // 16384 u16
    unsigned short* w2bt    = (unsigned short*)(ws + 23601152);  // 16384 u16
    unsigned short* wlt_pre = (unsigned short*)(ws + 23609344);  // 4096 u16
    unsigned short* ctb_pre = (unsigned short*)(ws + 23611392);  // 4096 u16
    unsigned short* wdft    = (unsigned short*)(ws + 23613440);  // 4352 u16
    unsigned short* e2k2    = (unsigned short*)(ws + 23615616);  // 16384 u16
    unsigned short* e2k4    = (unsigned short*)(ws + 23623808);  // 16384 u16

    k0_prep    <<<4096, 256, 0, stream>>>(ws0, ws1, w0cc, w1cc);
    k0b_prep   <<<305,  256, 0, stream>>>(wb1, wf1, wb2, wf2, wl,
                                          w1bt, w2bt, wlt_pre, ctb_pre, wdft,
                                          e2k2, e2k4);
    k1_dft_n   <<<4096, 256, 0, stream>>>(x, wdft, Ab);
    k2_dft_m   <<<512,  256, 0, stream>>>(Ab, e2k2, xftp);
    k3a_spec1  <<<1024, 256, 0, stream>>>(xftp, w0cc, c1p);
    k3b_spec2  <<<1024, 256, 0, stream>>>(c1p, w1cc, oftp);
    k4_idft_m  <<<512,  256, 0, stream>>>(oftp, e2k4, Tb);
    k56_fused  <<<2048, 256, 0, stream>>>(x, Tb, bl, ctb_pre, wlt_pre,
                                          w1bt, w2bt, bb1, bb2, bf1, bf2, out);
}